// Round 1
// baseline (2033.318 us; speedup 1.0000x reference)
//
#include <hip/hip_runtime.h>

#define LBUF 131072   // initial length, also channel stride of x buffers
#define TF   130048   // final time length

// fast tanh: tanh(a) = 1 - 2/(e^{2a}+1), clamped to avoid overflow
__device__ __forceinline__ float ftanh(float x) {
  float ax = fminf(fabsf(x), 15.0f);
  float t  = __expf(2.0f * ax);
  float r  = 1.0f - 2.0f / (t + 1.0f);
  return copysignf(r, x);
}

__global__ void k_init(const float* __restrict__ in, const float* __restrict__ w_init,
                       float* __restrict__ x) {
  int j = blockIdx.x * blockDim.x + threadIdx.x;
  if (j >= LBUF) return;
  float v = in[j];
#pragma unroll
  for (int c = 0; c < 32; ++c) x[c * LBUF + j] = w_init[c] * v;
}

__global__ void k_zero(float* __restrict__ p, int n) {
  int i = blockIdx.x * blockDim.x + threadIdx.x;
  if (i < n) p[i] = 0.0f;
}

__global__ __launch_bounds__(256) void k_layer(
    const float* __restrict__ xin, float* __restrict__ xout,
    float* __restrict__ skip,
    const float* __restrict__ wf, const float* __restrict__ wg,
    const float* __restrict__ wr, const float* __restrict__ wsk,
    int Tn, int d, int pad, int off_s)
{
  // weight staging: per-o rows so inner reads are broadcast float4s
  __shared__ float lwfg[32][128];  // [o][wf0/wf1 interleaved (64) | wg0/wg1 (64)]
  __shared__ float lwrT[32][32];   // [c][r]  (transposed 1x1 res weights)
  __shared__ float lwsT[32][16];   // [c][s]  (transposed skip weights)
  int tid = threadIdx.x;
  for (int i = tid; i < 2048; i += 256) {
    int o = i >> 6, cc = i & 63;
    lwfg[o][cc]      = wf[i];
    lwfg[o][64 + cc] = wg[i];
  }
  for (int i = tid; i < 1024; i += 256) lwrT[i & 31][i >> 5] = wr[i];
  for (int i = tid; i < 512;  i += 256) lwsT[i & 31][i >> 5] = wsk[i];
  __syncthreads();

  int j = blockIdx.x * 256 + tid;
  if (j >= Tn) return;
  int jl = j - pad;        // left tap (may be in zero padding)
  int jr = j + d - pad;    // right tap (always valid, also the residual)

  float xl[32], xr[32];
#pragma unroll
  for (int c = 0; c < 32; ++c) {
    xr[c] = xin[c * LBUF + jr];
    xl[c] = (jl >= 0) ? xin[c * LBUF + jl] : 0.0f;
  }

  float accS[16];
#pragma unroll
  for (int s = 0; s < 16; ++s) accS[s] = 0.0f;
  float accR[32];
#pragma unroll
  for (int r = 0; r < 32; ++r) accR[r] = xr[r];   // residual init

  for (int o = 0; o < 32; ++o) {   // NOT unrolled: keeps code size sane
    const float4* pf = (const float4*)(&lwfg[o][0]);
    const float4* pg = (const float4*)(&lwfg[o][64]);
    float uf = 0.0f, ug = 0.0f;
#pragma unroll
    for (int c4 = 0; c4 < 16; ++c4) {
      float4 a = pf[c4];  // wf0[2c4], wf1[2c4], wf0[2c4+1], wf1[2c4+1]
      uf += a.x * xl[2*c4] + a.y * xr[2*c4] + a.z * xl[2*c4+1] + a.w * xr[2*c4+1];
      float4 b = pg[c4];
      ug += b.x * xl[2*c4] + b.y * xr[2*c4] + b.z * xl[2*c4+1] + b.w * xr[2*c4+1];
    }
    float g = ftanh(uf) * ftanh(ug);
    const float4* pr = (const float4*)(&lwrT[o][0]);
#pragma unroll
    for (int r4 = 0; r4 < 8; ++r4) {
      float4 a = pr[r4];
      accR[4*r4+0] += a.x * g; accR[4*r4+1] += a.y * g;
      accR[4*r4+2] += a.z * g; accR[4*r4+3] += a.w * g;
    }
    const float4* ps = (const float4*)(&lwsT[o][0]);
#pragma unroll
    for (int s4 = 0; s4 < 4; ++s4) {
      float4 a = ps[s4];
      accS[4*s4+0] += a.x * g; accS[4*s4+1] += a.y * g;
      accS[4*s4+2] += a.z * g; accS[4*s4+3] += a.w * g;
    }
  }

  if (j >= off_s) {
    int js = j - off_s;
#pragma unroll
    for (int s = 0; s < 16; ++s) skip[s * TF + js] += accS[s];
  }
#pragma unroll
  for (int r = 0; r < 32; ++r) xout[r * LBUF + j] = accR[r];
}

// fused final: out = W2 @ relu(W1 @ relu(skip)); tile of 32 time positions/block
__global__ __launch_bounds__(256) void k_final(
    const float* __restrict__ skip,
    const float* __restrict__ w1, const float* __restrict__ w2,
    float* __restrict__ out)
{
  __shared__ float h1[256][33];   // 33 KB, padded stride vs bank conflicts
  int tid  = threadIdx.x;
  int grp  = tid >> 5;            // 8 groups of 32 lanes
  int lane = tid & 31;
  int j = blockIdx.x * 32 + lane;
  bool valid = (j < TF);

  float sk[16];
#pragma unroll
  for (int s = 0; s < 16; ++s)
    sk[s] = valid ? fmaxf(skip[s * TF + j], 0.0f) : 0.0f;

  // phase 1: h1[q1][lane] for q1 in this group's 32 rows
  for (int qi = 0; qi < 32; ++qi) {
    int q1 = grp * 32 + qi;
    const float4* pw = (const float4*)(&w1[q1 * 16]);
    float acc = 0.0f;
#pragma unroll
    for (int s4 = 0; s4 < 4; ++s4) {
      float4 a = pw[s4];
      acc += a.x * sk[4*s4] + a.y * sk[4*s4+1] + a.z * sk[4*s4+2] + a.w * sk[4*s4+3];
    }
    h1[q1][lane] = fmaxf(acc, 0.0f);
  }
  __syncthreads();

  // phase 2: out rows q in this group's 32, 8 at a time
  for (int qq = 0; qq < 32; qq += 8) {
    int q = grp * 32 + qq;
    float acc[8];
#pragma unroll
    for (int i = 0; i < 8; ++i) acc[i] = 0.0f;
    for (int q1 = 0; q1 < 256; ++q1) {
      float h = h1[q1][lane];
#pragma unroll
      for (int i = 0; i < 8; ++i) acc[i] += w2[(q + i) * 256 + q1] * h;
    }
    if (valid) {
#pragma unroll
      for (int i = 0; i < 8; ++i) out[(q + i) * TF + j] = acc[i];
    }
  }
}

extern "C" void kernel_launch(void* const* d_in, const int* in_sizes, int n_in,
                              void* d_out, int out_size, void* d_ws, size_t ws_size,
                              hipStream_t stream) {
  const float* x_in     = (const float*)d_in[0];
  const float* w_init   = (const float*)d_in[1];
  const float* w_filter = (const float*)d_in[2];
  const float* w_gate   = (const float*)d_in[3];
  const float* w_res    = (const float*)d_in[4];
  const float* w_skip   = (const float*)d_in[5];
  const float* w_f1     = (const float*)d_in[6];
  const float* w_f2     = (const float*)d_in[7];
  float* out = (float*)d_out;

  float* xa    = (float*)d_ws;            // 32 x 131072 fp32 = 16 MB
  float* xb    = xa + 32 * (size_t)LBUF;  // 16 MB
  float* skipb = xb + 32 * (size_t)LBUF;  // 16 x 130048 fp32 ~ 8.3 MB

  k_init<<<(LBUF + 255) / 256, 256, 0, stream>>>(x_in, w_init, xa);
  k_zero<<<(16 * TF + 255) / 256, 256, 0, stream>>>(skipb, 16 * TF);

  int T = LBUF;
  for (int idx = 0; idx < 20; ++idx) {
    int d    = 1 << (idx % 10);
    int pad  = (d - (T % d)) % d;
    int Tn   = T + pad - d;
    int offs = Tn - TF;
    k_layer<<<(Tn + 255) / 256, 256, 0, stream>>>(
        xa, xb, skipb,
        w_filter + (size_t)idx * 2048, w_gate + (size_t)idx * 2048,
        w_res + (size_t)idx * 1024, w_skip + (size_t)idx * 512,
        Tn, d, pad, offs);
    float* t = xa; xa = xb; xb = t;
    T = Tn;
  }

  k_final<<<(TF + 31) / 32, 256, 0, stream>>>(skipb, w_f1, w_f2, out);
}

// Round 3
// 1911.113 us; speedup vs baseline: 1.0639x; 1.0639x over previous
//
#include <hip/hip_runtime.h>

#define LBUF 131072   // initial length, channel stride of x buffers
#define TF   130048   // final time length (= 2032 * 64)

// fast tanh: tanh(a) = 1 - 2/(e^{2a}+1), clamped to avoid overflow
__device__ __forceinline__ float ftanh(float x) {
  float ax = fminf(fabsf(x), 15.0f);
  float t  = __expf(2.0f * ax);
  float r  = 1.0f - 2.0f / (t + 1.0f);
  return copysignf(r, x);
}

__device__ __forceinline__ float frelu(float x) { return fmaxf(x, 0.0f); }

__global__ void k_init(const float* __restrict__ in, const float* __restrict__ w_init,
                       float* __restrict__ x) {
  int j = blockIdx.x * blockDim.x + threadIdx.x;
  if (j >= LBUF) return;
  float v = in[j];
#pragma unroll
  for (int c = 0; c < 32; ++c) x[c * LBUF + j] = w_init[c] * v;
}

// One dilated-conv layer. Weights read with wave-uniform indices -> SGPR loads.
__global__ __launch_bounds__(256) void k_layer(
    const float* __restrict__ xin, float* __restrict__ xout,
    float* __restrict__ skip,
    const float* __restrict__ wf, const float* __restrict__ wg,
    const float* __restrict__ wr, const float* __restrict__ wsk,
    int Tn, int d, int pad, int off_s, int first, int writex)
{
  int j = blockIdx.x * 256 + threadIdx.x;
  if (j >= Tn) return;
  int jl = j - pad;        // left tap (may fall in left zero-padding)
  int jr = j + d - pad;    // right tap (always valid; also the residual source)

  float xl[32], xr[32];
#pragma unroll
  for (int c = 0; c < 32; ++c) {
    xr[c] = xin[c * LBUF + jr];
    xl[c] = (jl >= 0) ? xin[c * LBUF + jl] : 0.0f;
  }

  float accS[16];
#pragma unroll
  for (int s = 0; s < 16; ++s) accS[s] = 0.0f;
  float accR[32];
#pragma unroll
  for (int r = 0; r < 32; ++r) accR[r] = xr[r];   // residual init

  for (int ob = 0; ob < 4; ++ob) {      // 4 chunks of 8 dilation channels
    float g[8];
#pragma unroll
    for (int oo = 0; oo < 8; ++oo) {
      const float* pf = wf + (ob * 8 + oo) * 64;  // [c][tap] interleaved row
      const float* pg = wg + (ob * 8 + oo) * 64;
      float uf0 = 0, uf1 = 0, uf2 = 0, uf3 = 0;
      float ug0 = 0, ug1 = 0, ug2 = 0, ug3 = 0;
#pragma unroll
      for (int c = 0; c < 32; c += 4) {
        uf0 += pf[2*c+0] * xl[c+0] + pf[2*c+1] * xr[c+0];
        uf1 += pf[2*c+2] * xl[c+1] + pf[2*c+3] * xr[c+1];
        uf2 += pf[2*c+4] * xl[c+2] + pf[2*c+5] * xr[c+2];
        uf3 += pf[2*c+6] * xl[c+3] + pf[2*c+7] * xr[c+3];
        ug0 += pg[2*c+0] * xl[c+0] + pg[2*c+1] * xr[c+0];
        ug1 += pg[2*c+2] * xl[c+1] + pg[2*c+3] * xr[c+1];
        ug2 += pg[2*c+4] * xl[c+2] + pg[2*c+5] * xr[c+2];
        ug3 += pg[2*c+6] * xl[c+3] + pg[2*c+7] * xr[c+3];
      }
      g[oo] = ftanh((uf0 + uf1) + (uf2 + uf3)) * ftanh((ug0 + ug1) + (ug2 + ug3));
    }
    const float* prr = wr  + ob * 8;   // wr[r][o] rows, contiguous 8-chunk in o
    const float* pss = wsk + ob * 8;
    if (writex) {
#pragma unroll
      for (int r = 0; r < 32; ++r) {
        float a = prr[r*32+0]*g[0] + prr[r*32+1]*g[1] + prr[r*32+2]*g[2] + prr[r*32+3]*g[3]
                + prr[r*32+4]*g[4] + prr[r*32+5]*g[5] + prr[r*32+6]*g[6] + prr[r*32+7]*g[7];
        accR[r] += a;
      }
    }
#pragma unroll
    for (int s = 0; s < 16; ++s) {
      float a = pss[s*32+0]*g[0] + pss[s*32+1]*g[1] + pss[s*32+2]*g[2] + pss[s*32+3]*g[3]
              + pss[s*32+4]*g[4] + pss[s*32+5]*g[5] + pss[s*32+6]*g[6] + pss[s*32+7]*g[7];
      accS[s] += a;
    }
  }

  if (j >= off_s) {
    int js = j - off_s;
    if (first) {
#pragma unroll
      for (int s = 0; s < 16; ++s) skip[s * TF + js] = accS[s];
    } else {
#pragma unroll
      for (int s = 0; s < 16; ++s) skip[s * TF + js] += accS[s];
    }
  }
  if (writex) {
#pragma unroll
    for (int r = 0; r < 32; ++r) xout[r * LBUF + j] = accR[r];
  }
}

// Fused final MLP: out = W2 @ relu(W1 @ relu(skip)). Tiled LDS GEMM.
// Block: 64 time cols x all 256 out rows; threads (ty 0..31) x (tx 0..7), 8x8 per thread.
__global__ __launch_bounds__(256) void k_final(
    const float* __restrict__ skip,
    const float* __restrict__ w1, const float* __restrict__ w2,
    float* __restrict__ out)
{
  __shared__ float sk[16][64];     // relu(skip) tile
  __shared__ float h1[256][64];    // 64 KB
  __shared__ float w2t[64][260];   // transposed W2 k-chunk, padded rows (66.6 KB)

  int tid = threadIdx.x;
  int jb  = blockIdx.x * 64;
  int ty  = tid >> 3;              // 0..31 -> output-row group (8 rows)
  int tx  = tid & 7;               // 0..7  -> time-col group (8 cols)

  for (int i = tid; i < 1024; i += 256) {
    int s = i >> 6, jc = i & 63;
    sk[s][jc] = frelu(skip[s * TF + jb + jc]);
  }
  __syncthreads();

  // GEMM1: h1[q1][j] = relu( sum_s W1[q1][s] * sk[s][j] ), K=16
  {
    float acc1[8][8];
#pragma unroll
    for (int i = 0; i < 8; ++i)
#pragma unroll
      for (int c = 0; c < 8; ++c) acc1[i][c] = 0.0f;

#pragma unroll
    for (int s = 0; s < 16; ++s) {
      float a[8];
#pragma unroll
      for (int i = 0; i < 8; ++i) a[i] = w1[(ty * 8 + i) * 16 + s];
      float4 b0 = *(const float4*)&sk[s][tx * 8];
      float4 b1 = *(const float4*)&sk[s][tx * 8 + 4];
      float b[8] = {b0.x, b0.y, b0.z, b0.w, b1.x, b1.y, b1.z, b1.w};
#pragma unroll
      for (int i = 0; i < 8; ++i)
#pragma unroll
        for (int c = 0; c < 8; ++c) acc1[i][c] += a[i] * b[c];
    }
#pragma unroll
    for (int i = 0; i < 8; ++i) {
      float4 h0 = {frelu(acc1[i][0]), frelu(acc1[i][1]), frelu(acc1[i][2]), frelu(acc1[i][3])};
      float4 h4 = {frelu(acc1[i][4]), frelu(acc1[i][5]), frelu(acc1[i][6]), frelu(acc1[i][7])};
      *(float4*)&h1[ty * 8 + i][tx * 8]     = h0;
      *(float4*)&h1[ty * 8 + i][tx * 8 + 4] = h4;
    }
  }

  // GEMM2: out = W2 @ h1, K=256 in 4 chunks of 64
  float acc2[8][8];
#pragma unroll
  for (int i = 0; i < 8; ++i)
#pragma unroll
    for (int c = 0; c < 8; ++c) acc2[i][c] = 0.0f;

  int kk4 = tid & 15;   // k-group for staging
  int q0  = tid >> 4;   // q-base for staging
  for (int kb = 0; kb < 4; ++kb) {
    __syncthreads();   // prev compute done (and h1 stores) before overwriting w2t
#pragma unroll
    for (int rep = 0; rep < 16; ++rep) {
      int q = q0 + rep * 16;
      const float4 v = *(const float4*)&w2[q * 256 + kb * 64 + kk4 * 4];
      w2t[kk4 * 4 + 0][q] = v.x;
      w2t[kk4 * 4 + 1][q] = v.y;
      w2t[kk4 * 4 + 2][q] = v.z;
      w2t[kk4 * 4 + 3][q] = v.w;
    }
    __syncthreads();
#pragma unroll 4
    for (int k = 0; k < 64; ++k) {
      float4 a0 = *(const float4*)&w2t[k][ty * 8];
      float4 a1 = *(const float4*)&w2t[k][ty * 8 + 4];
      float4 b0 = *(const float4*)&h1[kb * 64 + k][tx * 8];
      float4 b1 = *(const float4*)&h1[kb * 64 + k][tx * 8 + 4];
      float a[8] = {a0.x, a0.y, a0.z, a0.w, a1.x, a1.y, a1.z, a1.w};
      float b[8] = {b0.x, b0.y, b0.z, b0.w, b1.x, b1.y, b1.z, b1.w};
#pragma unroll
      for (int i = 0; i < 8; ++i)
#pragma unroll
        for (int c = 0; c < 8; ++c) acc2[i][c] += a[i] * b[c];
    }
  }

#pragma unroll
  for (int i = 0; i < 8; ++i) {
    int q = ty * 8 + i;
    float4 o0 = {acc2[i][0], acc2[i][1], acc2[i][2], acc2[i][3]};
    float4 o1 = {acc2[i][4], acc2[i][5], acc2[i][6], acc2[i][7]};
    *(float4*)&out[(size_t)q * TF + jb + tx * 8]     = o0;
    *(float4*)&out[(size_t)q * TF + jb + tx * 8 + 4] = o1;
  }
}

extern "C" void kernel_launch(void* const* d_in, const int* in_sizes, int n_in,
                              void* d_out, int out_size, void* d_ws, size_t ws_size,
                              hipStream_t stream) {
  const float* x_in     = (const float*)d_in[0];
  const float* w_init   = (const float*)d_in[1];
  const float* w_filter = (const float*)d_in[2];
  const float* w_gate   = (const float*)d_in[3];
  const float* w_res    = (const float*)d_in[4];
  const float* w_skip   = (const float*)d_in[5];
  const float* w_f1     = (const float*)d_in[6];
  const float* w_f2     = (const float*)d_in[7];
  float* out = (float*)d_out;

  float* xa    = (float*)d_ws;            // 32 x 131072 fp32 = 16 MB
  float* xb    = xa + 32 * (size_t)LBUF;  // 16 MB
  float* skipb = xb + 32 * (size_t)LBUF;  // 16 x 130048 fp32 ~ 8.3 MB

  k_init<<<(LBUF + 255) / 256, 256, 0, stream>>>(x_in, w_init, xa);

  int T = LBUF;
  for (int idx = 0; idx < 20; ++idx) {
    int d    = 1 << (idx % 10);
    int pad  = (d - (T % d)) % d;
    int Tn   = T + pad - d;
    int offs = Tn - TF;
    k_layer<<<(Tn + 255) / 256, 256, 0, stream>>>(
        xa, xb, skipb,
        w_filter + (size_t)idx * 2048, w_gate + (size_t)idx * 2048,
        w_res + (size_t)idx * 1024, w_skip + (size_t)idx * 512,
        Tn, d, pad, offs, (idx == 0) ? 1 : 0, (idx == 19) ? 0 : 1);
    float* t = xa; xa = xb; xb = t;
    T = Tn;
  }

  k_final<<<TF / 64, 256, 0, stream>>>(skipb, w_f1, w_f2, out);
}

// Round 4
// 1481.743 us; speedup vs baseline: 1.3722x; 1.2898x over previous
//
#include <hip/hip_runtime.h>

#define LBUF 131072   // channel stride of x buffers
#define TF   130048   // final time length
#define TB   128      // time-tile per block in k_layer

// fast tanh: tanh(a) = 1 - 2/(e^{2a}+1), clamped to avoid overflow
__device__ __forceinline__ float ftanh(float x) {
  float ax = fminf(fabsf(x), 15.0f);
  float t  = __expf(2.0f * ax);
  float r  = 1.0f - 2.0f / (t + 1.0f);
  return copysignf(r, x);
}

__device__ __forceinline__ float frelu(float x) { return fmaxf(x, 0.0f); }

__global__ void k_init(const float* __restrict__ in, const float* __restrict__ w_init,
                       float* __restrict__ x) {
  int j = blockIdx.x * blockDim.x + threadIdx.x;
  if (j >= LBUF) return;
  float v = in[j];
#pragma unroll
  for (int c = 0; c < 32; ++c) x[c * LBUF + j] = w_init[c] * v;
}

// One dilated layer as two LDS-tiled GEMMs.
// GEMM1: u[64][TB] = Wt[64k][64m] x Xs[64][TB]   (m: 2o=filter,2o+1=gate; k: 2c+tap)
// gate:  G[32][TB] = tanh(f)*tanh(g)
// GEMM2: [res(32);skip(16)][TB] = W2t[32k][48m] x G
__global__ __launch_bounds__(256) void k_layer(
    const float* __restrict__ xin, float* __restrict__ xout,
    float* __restrict__ skip,
    const float* __restrict__ wf, const float* __restrict__ wg,
    const float* __restrict__ wr, const float* __restrict__ wsk,
    int Tn, int Told, int d, int pad, int off_s, int first, int writex)
{
  __shared__ float Xs[64][TB + 4];   // rows 2c+tap: tap0 = x[j-pad], tap1 = x[j+d-pad]
  __shared__ float Gs[32][TB + 4];
  __shared__ float Wt[64][68];       // [k][m]
  __shared__ float W2t[32][52];      // [k=o][m: 0..31 res, 32..47 skip]

  int tid = threadIdx.x;
  int jb  = blockIdx.x * TB;

  // ---- stage weights (transposed for broadcast k-row reads) ----
  for (int i = tid; i < 2048; i += 256) {
    int o = i >> 6, k = i & 63;
    Wt[k][2 * o]     = wf[i];
    Wt[k][2 * o + 1] = wg[i];
  }
  for (int i = tid; i < 1024; i += 256) W2t[i & 31][i >> 5] = wr[i];
  for (int i = tid; i < 512;  i += 256) W2t[i & 31][32 + (i >> 5)] = wsk[i];

  // ---- stage X tile: 64 rows x TB cols, coalesced scalar loads ----
  for (int i = tid; i < 64 * TB; i += 256) {
    int row = i >> 7, col = i & (TB - 1);
    int c = row >> 1;
    int e = jb + col - pad + ((row & 1) ? d : 0);
    Xs[row][col] = (e >= 0 && e < Told) ? xin[c * LBUF + e] : 0.0f;
  }
  __syncthreads();

  // ---- GEMM1: 4M x 8N per thread (cols tn*4..+3 and tn*4+64..+67) ----
  int tn = tid & 15, tm = tid >> 4;    // tm 0..15 (4 rows each), tn 0..15
  float acc[4][8];
#pragma unroll
  for (int i = 0; i < 4; ++i)
#pragma unroll
    for (int q = 0; q < 8; ++q) acc[i][q] = 0.0f;

#pragma unroll 8
  for (int k = 0; k < 64; ++k) {
    float4 a  = *(const float4*)&Wt[k][tm * 4];
    float4 b0 = *(const float4*)&Xs[k][tn * 4];
    float4 b1 = *(const float4*)&Xs[k][tn * 4 + 64];
    float av[4] = {a.x, a.y, a.z, a.w};
    float bv[8] = {b0.x, b0.y, b0.z, b0.w, b1.x, b1.y, b1.z, b1.w};
#pragma unroll
    for (int i = 0; i < 4; ++i)
#pragma unroll
      for (int q = 0; q < 8; ++q) acc[i][q] += av[i] * bv[q];
  }

  // ---- gate: rows (4tm,4tm+1)->o=2tm ; (4tm+2,4tm+3)->o=2tm+1 ----
  {
    float g0[8], g1[8];
#pragma unroll
    for (int q = 0; q < 8; ++q) {
      g0[q] = ftanh(acc[0][q]) * ftanh(acc[1][q]);
      g1[q] = ftanh(acc[2][q]) * ftanh(acc[3][q]);
    }
    *(float4*)&Gs[2 * tm][tn * 4]          = *(float4*)&g0[0];
    *(float4*)&Gs[2 * tm][tn * 4 + 64]     = *(float4*)&g0[4];
    *(float4*)&Gs[2 * tm + 1][tn * 4]      = *(float4*)&g1[0];
    *(float4*)&Gs[2 * tm + 1][tn * 4 + 64] = *(float4*)&g1[4];
  }
  __syncthreads();

  // ---- GEMM2: 12M x 2N per thread; tm2 wave-uniform ----
  int tn2 = tid & 63, tm2 = tid >> 6;  // tm2 0..3: rows tm2*12..+11
  float acc2[12][2];
#pragma unroll
  for (int i = 0; i < 12; ++i) { acc2[i][0] = 0.0f; acc2[i][1] = 0.0f; }

#pragma unroll 4
  for (int k = 0; k < 32; ++k) {
    float4 a0 = *(const float4*)&W2t[k][tm2 * 12];
    float4 a1 = *(const float4*)&W2t[k][tm2 * 12 + 4];
    float4 a2 = *(const float4*)&W2t[k][tm2 * 12 + 8];
    float2 b  = *(const float2*)&Gs[k][tn2 * 2];
    float av[12] = {a0.x, a0.y, a0.z, a0.w, a1.x, a1.y, a1.z, a1.w, a2.x, a2.y, a2.z, a2.w};
#pragma unroll
    for (int i = 0; i < 12; ++i) {
      acc2[i][0] += av[i] * b.x;
      acc2[i][1] += av[i] * b.y;
    }
  }

  // ---- epilogue ----
  int j0 = jb + tn2 * 2;
#pragma unroll
  for (int i = 0; i < 12; ++i) {
    int m = tm2 * 12 + i;            // wave-uniform
    if (m < 32) {
      if (writex) {
        // residual = right tap = Xs[2m+1][col]
        float v0 = acc2[i][0] + Xs[2 * m + 1][tn2 * 2];
        float v1 = acc2[i][1] + Xs[2 * m + 1][tn2 * 2 + 1];
        if (j0 + 1 < Tn) {
          float2 v = {v0, v1};
          *(float2*)&xout[(size_t)m * LBUF + j0] = v;
        } else if (j0 < Tn) {
          xout[(size_t)m * LBUF + j0] = v0;
        }
      }
    } else {
      int s = m - 32;
      int js = j0 - off_s;
      if (first) {
        if (js >= 0 && j0 < Tn)         skip[(size_t)s * TF + js]     = acc2[i][0];
        if (js + 1 >= 0 && j0 + 1 < Tn) skip[(size_t)s * TF + js + 1] = acc2[i][1];
      } else {
        if (js >= 0 && j0 < Tn)         skip[(size_t)s * TF + js]     += acc2[i][0];
        if (js + 1 >= 0 && j0 + 1 < Tn) skip[(size_t)s * TF + js + 1] += acc2[i][1];
      }
    }
  }
}

// Fused final MLP: out = W2 @ relu(W1 @ relu(skip)). Tiled LDS GEMM.
__global__ __launch_bounds__(256) void k_final(
    const float* __restrict__ skip,
    const float* __restrict__ w1, const float* __restrict__ w2,
    float* __restrict__ out)
{
  __shared__ float sk[16][64];
  __shared__ float h1[256][64];
  __shared__ float w2t[64][260];

  int tid = threadIdx.x;
  int jb  = blockIdx.x * 64;
  int ty  = tid >> 3;
  int tx  = tid & 7;

  for (int i = tid; i < 1024; i += 256) {
    int s = i >> 6, jc = i & 63;
    sk[s][jc] = frelu(skip[s * TF + jb + jc]);
  }
  __syncthreads();

  {
    float acc1[8][8];
#pragma unroll
    for (int i = 0; i < 8; ++i)
#pragma unroll
      for (int c = 0; c < 8; ++c) acc1[i][c] = 0.0f;

#pragma unroll
    for (int s = 0; s < 16; ++s) {
      float a[8];
#pragma unroll
      for (int i = 0; i < 8; ++i) a[i] = w1[(ty * 8 + i) * 16 + s];
      float4 b0 = *(const float4*)&sk[s][tx * 8];
      float4 b1 = *(const float4*)&sk[s][tx * 8 + 4];
      float b[8] = {b0.x, b0.y, b0.z, b0.w, b1.x, b1.y, b1.z, b1.w};
#pragma unroll
      for (int i = 0; i < 8; ++i)
#pragma unroll
        for (int c = 0; c < 8; ++c) acc1[i][c] += a[i] * b[c];
    }
#pragma unroll
    for (int i = 0; i < 8; ++i) {
      float4 h0 = {frelu(acc1[i][0]), frelu(acc1[i][1]), frelu(acc1[i][2]), frelu(acc1[i][3])};
      float4 h4 = {frelu(acc1[i][4]), frelu(acc1[i][5]), frelu(acc1[i][6]), frelu(acc1[i][7])};
      *(float4*)&h1[ty * 8 + i][tx * 8]     = h0;
      *(float4*)&h1[ty * 8 + i][tx * 8 + 4] = h4;
    }
  }

  float acc2[8][8];
#pragma unroll
  for (int i = 0; i < 8; ++i)
#pragma unroll
    for (int c = 0; c < 8; ++c) acc2[i][c] = 0.0f;

  int kk4 = tid & 15;
  int q0  = tid >> 4;
  for (int kb = 0; kb < 4; ++kb) {
    __syncthreads();
#pragma unroll
    for (int rep = 0; rep < 16; ++rep) {
      int q = q0 + rep * 16;
      const float4 v = *(const float4*)&w2[q * 256 + kb * 64 + kk4 * 4];
      w2t[kk4 * 4 + 0][q] = v.x;
      w2t[kk4 * 4 + 1][q] = v.y;
      w2t[kk4 * 4 + 2][q] = v.z;
      w2t[kk4 * 4 + 3][q] = v.w;
    }
    __syncthreads();
#pragma unroll 4
    for (int k = 0; k < 64; ++k) {
      float4 a0 = *(const float4*)&w2t[k][ty * 8];
      float4 a1 = *(const float4*)&w2t[k][ty * 8 + 4];
      float4 b0 = *(const float4*)&h1[kb * 64 + k][tx * 8];
      float4 b1 = *(const float4*)&h1[kb * 64 + k][tx * 8 + 4];
      float a[8] = {a0.x, a0.y, a0.z, a0.w, a1.x, a1.y, a1.z, a1.w};
      float b[8] = {b0.x, b0.y, b0.z, b0.w, b1.x, b1.y, b1.z, b1.w};
#pragma unroll
      for (int i = 0; i < 8; ++i)
#pragma unroll
        for (int c = 0; c < 8; ++c) acc2[i][c] += a[i] * b[c];
    }
  }

#pragma unroll
  for (int i = 0; i < 8; ++i) {
    int q = ty * 8 + i;
    float4 o0 = {acc2[i][0], acc2[i][1], acc2[i][2], acc2[i][3]};
    float4 o1 = {acc2[i][4], acc2[i][5], acc2[i][6], acc2[i][7]};
    *(float4*)&out[(size_t)q * TF + jb + tx * 8]     = o0;
    *(float4*)&out[(size_t)q * TF + jb + tx * 8 + 4] = o1;
  }
}

extern "C" void kernel_launch(void* const* d_in, const int* in_sizes, int n_in,
                              void* d_out, int out_size, void* d_ws, size_t ws_size,
                              hipStream_t stream) {
  const float* x_in     = (const float*)d_in[0];
  const float* w_init   = (const float*)d_in[1];
  const float* w_filter = (const float*)d_in[2];
  const float* w_gate   = (const float*)d_in[3];
  const float* w_res    = (const float*)d_in[4];
  const float* w_skip   = (const float*)d_in[5];
  const float* w_f1     = (const float*)d_in[6];
  const float* w_f2     = (const float*)d_in[7];
  float* out = (float*)d_out;

  float* xa    = (float*)d_ws;            // 32 x 131072 fp32
  float* xb    = xa + 32 * (size_t)LBUF;
  float* skipb = xb + 32 * (size_t)LBUF;  // 16 x 130048 fp32

  k_init<<<(LBUF + 255) / 256, 256, 0, stream>>>(x_in, w_init, xa);

  int T = LBUF;
  for (int idx = 0; idx < 20; ++idx) {
    int d    = 1 << (idx % 10);
    int pad  = (d - (T % d)) % d;
    int Tn   = T + pad - d;
    int offs = Tn - TF;
    k_layer<<<(Tn + TB - 1) / TB, 256, 0, stream>>>(
        xa, xb, skipb,
        w_filter + (size_t)idx * 2048, w_gate + (size_t)idx * 2048,
        w_res + (size_t)idx * 1024, w_skip + (size_t)idx * 512,
        Tn, T, d, pad, offs, (idx == 0) ? 1 : 0, (idx == 19) ? 0 : 1);
    float* t = xa; xa = xb; xb = t;
    T = Tn;
  }

  k_final<<<TF / 64, 256, 0, stream>>>(skipb, w_f1, w_f2, out);
}

// Round 6
// 1394.644 us; speedup vs baseline: 1.4579x; 1.0625x over previous
//
#include <hip/hip_runtime.h>

#define LBUF 131072   // channel stride of x buffers
#define TF   130048   // final time length (= 2032 * 64)
#define TB   64       // time-tile per block in k_layer

typedef short bf16x8 __attribute__((ext_vector_type(8)));
typedef float f32x4  __attribute__((ext_vector_type(4)));

// fast tanh: tanh(a) = 1 - 2/(e^{2a}+1), clamped
__device__ __forceinline__ float ftanh(float x) {
  float ax = fminf(fabsf(x), 15.0f);
  float t  = __expf(2.0f * ax);
  float r  = 1.0f - 2.0f / (t + 1.0f);
  return copysignf(r, x);
}

// fp32 -> bf16 RNE
__device__ __forceinline__ unsigned short b16(float f) {
  unsigned u = __builtin_bit_cast(unsigned, f);
  return (unsigned short)((u + 0x7fffu + ((u >> 16) & 1u)) >> 16);
}
__device__ __forceinline__ float bf2f(unsigned short h) {
  return __builtin_bit_cast(float, ((unsigned)h) << 16);
}
__device__ __forceinline__ unsigned pack2(float v0, float v1,
                                          unsigned short* lo0, unsigned short* lo1) {
  unsigned short h0 = b16(v0), h1 = b16(v1);
  *lo0 = b16(v0 - bf2f(h0));
  *lo1 = b16(v1 - bf2f(h1));
  return (unsigned)h0 | ((unsigned)h1 << 16);
}

__global__ void k_init(const float* __restrict__ in, const float* __restrict__ w_init,
                       float* __restrict__ x) {
  int j = blockIdx.x * blockDim.x + threadIdx.x;
  if (j >= LBUF) return;
  float v = in[j];
#pragma unroll
  for (int c = 0; c < 32; ++c) x[c * LBUF + j] = w_init[c] * v;
}

// One dilated layer, split-bf16 MFMA (3-term emulated fp32).
// GEMM1: u[64m][64] = W[64m][64k] x X[64k][64]  (m 0..31 filter, 32..63 gate; k=2c+tap)
// GEMM2: [res32; skip16][64] = W2[48][32o] x G[32o][64]
// 4 waves; wave w owns 16 cols (one n-tile).
__global__ __launch_bounds__(256) void k_layer(
    const float* __restrict__ xin, float* __restrict__ xout,
    float* __restrict__ skip,
    const float* __restrict__ wf, const float* __restrict__ wg,
    const float* __restrict__ wr, const float* __restrict__ wsk,
    int Tn, int Told, int d, int pad, int off_s, int first, int writex)
{
  __shared__ unsigned short Xh[TB][72], Xl[TB][72];   // [col][k]
  __shared__ unsigned short Gh[TB][40], Gl[TB][40];   // [col][o]
  __shared__ unsigned short Wh[64][72], Wl[64][72];   // [m][k]
  __shared__ unsigned short W2h[48][40], W2l[48][40]; // [m'][o]

  int tid = threadIdx.x;
  int jb  = blockIdx.x * TB;

  // ---- stage conv weights: 4096 vals as 2048 (hi,lo) pairs ----
  for (int i = tid; i < 2048; i += 256) {
    int m = i >> 5, k2 = i & 31;
    const float* src = (m < 32) ? (wf + m * 64) : (wg + (m - 32) * 64);
    float v0 = src[2 * k2], v1 = src[2 * k2 + 1];
    unsigned short l0, l1;
    unsigned ph = pack2(v0, v1, &l0, &l1);
    *(unsigned*)&Wh[m][2 * k2] = ph;
    *(unsigned*)&Wl[m][2 * k2] = (unsigned)l0 | ((unsigned)l1 << 16);
  }
  // ---- stage 1x1 weights: 1536 vals ----
  for (int i = tid; i < 768; i += 256) {
    int m = i >> 4, o2 = i & 15;
    const float* src = (m < 32) ? (wr + m * 32) : (wsk + (m - 32) * 32);
    float v0 = src[2 * o2], v1 = src[2 * o2 + 1];
    unsigned short l0, l1;
    unsigned ph = pack2(v0, v1, &l0, &l1);
    *(unsigned*)&W2h[m][2 * o2] = ph;
    *(unsigned*)&W2l[m][2 * o2] = (unsigned)l0 | ((unsigned)l1 << 16);
  }
  // ---- stage X tile: k-pairs (tap0,tap1) per c ----
  for (int i = tid; i < 32 * TB; i += 256) {
    int col = i & (TB - 1), c = i >> 6;
    int e0 = jb + col - pad;
    int e1 = e0 + d;
    float v0 = (e0 >= 0 && e0 < Told) ? xin[(size_t)c * LBUF + e0] : 0.0f;
    float v1 = (e1 >= 0 && e1 < Told) ? xin[(size_t)c * LBUF + e1] : 0.0f;
    unsigned short l0, l1;
    unsigned ph = pack2(v0, v1, &l0, &l1);
    *(unsigned*)&Xh[col][2 * c] = ph;
    *(unsigned*)&Xl[col][2 * c] = (unsigned)l0 | ((unsigned)l1 << 16);
  }
  __syncthreads();

  int lane = tid & 63, w = tid >> 6;
  int lr = lane & 15;   // row/col within 16-tile
  int lg = lane >> 4;   // k-group 0..3

  // ---- GEMM1: acc1[mt] over K=64 (2 k-steps), 3-term split ----
  f32x4 acc1[4];
#pragma unroll
  for (int mt = 0; mt < 4; ++mt) acc1[mt] = (f32x4){0.f, 0.f, 0.f, 0.f};

#pragma unroll
  for (int ks = 0; ks < 2; ++ks) {
    const char* xb = (const char*)&Xh[0][0] + (w * 16 + lr) * 144 + ks * 64 + lg * 16;
    const char* xl = (const char*)&Xl[0][0] + (w * 16 + lr) * 144 + ks * 64 + lg * 16;
    bf16x8 bh = *(const bf16x8*)xb;
    bf16x8 bl = *(const bf16x8*)xl;
#pragma unroll
    for (int mt = 0; mt < 4; ++mt) {
      const char* wb = (const char*)&Wh[0][0] + (mt * 16 + lr) * 144 + ks * 64 + lg * 16;
      const char* wlp = (const char*)&Wl[0][0] + (mt * 16 + lr) * 144 + ks * 64 + lg * 16;
      bf16x8 ah = *(const bf16x8*)wb;
      bf16x8 al = *(const bf16x8*)wlp;
      acc1[mt] = __builtin_amdgcn_mfma_f32_16x16x32_bf16(ah, bh, acc1[mt], 0, 0, 0);
      acc1[mt] = __builtin_amdgcn_mfma_f32_16x16x32_bf16(ah, bl, acc1[mt], 0, 0, 0);
      acc1[mt] = __builtin_amdgcn_mfma_f32_16x16x32_bf16(al, bh, acc1[mt], 0, 0, 0);
    }
  }

  // ---- gate -> Gh/Gl (wave-local cols) ----
  {
    int col = w * 16 + lr;
#pragma unroll
    for (int t = 0; t < 2; ++t) {
      float g0 = ftanh(acc1[t][0]) * ftanh(acc1[t + 2][0]);
      float g1 = ftanh(acc1[t][1]) * ftanh(acc1[t + 2][1]);
      float g2 = ftanh(acc1[t][2]) * ftanh(acc1[t + 2][2]);
      float g3 = ftanh(acc1[t][3]) * ftanh(acc1[t + 2][3]);
      int o0 = t * 16 + lg * 4;
      unsigned short l0, l1, l2, l3;
      unsigned p01 = pack2(g0, g1, &l0, &l1);
      unsigned p23 = pack2(g2, g3, &l2, &l3);
      *(unsigned*)&Gh[col][o0]     = p01;
      *(unsigned*)&Gh[col][o0 + 2] = p23;
      *(unsigned*)&Gl[col][o0]     = (unsigned)l0 | ((unsigned)l1 << 16);
      *(unsigned*)&Gl[col][o0 + 2] = (unsigned)l2 | ((unsigned)l3 << 16);
    }
  }

  // ---- GEMM2: K=32 (1 k-step), 3-term split; wave-local ----
  f32x4 acc2[3];
  {
    const char* gb = (const char*)&Gh[0][0] + (w * 16 + lr) * 80 + lg * 16;
    const char* gl = (const char*)&Gl[0][0] + (w * 16 + lr) * 80 + lg * 16;
    bf16x8 bh = *(const bf16x8*)gb;
    bf16x8 bl = *(const bf16x8*)gl;
#pragma unroll
    for (int mt = 0; mt < 3; ++mt) {
      const char* ab = (const char*)&W2h[0][0] + (mt * 16 + lr) * 80 + lg * 16;
      const char* albp = (const char*)&W2l[0][0] + (mt * 16 + lr) * 80 + lg * 16;
      bf16x8 ah = *(const bf16x8*)ab;
      bf16x8 al = *(const bf16x8*)albp;
      f32x4 z = {0.f, 0.f, 0.f, 0.f};
      z = __builtin_amdgcn_mfma_f32_16x16x32_bf16(ah, bh, z, 0, 0, 0);
      z = __builtin_amdgcn_mfma_f32_16x16x32_bf16(ah, bl, z, 0, 0, 0);
      acc2[mt] = __builtin_amdgcn_mfma_f32_16x16x32_bf16(al, bh, z, 0, 0, 0);
    }
  }

  // ---- epilogue ----
  {
    int j = jb + w * 16 + lr;
    if (j < Tn) {
      if (writex) {
#pragma unroll
        for (int mt = 0; mt < 2; ++mt)
#pragma unroll
          for (int i = 0; i < 4; ++i) {
            int m = mt * 16 + lg * 4 + i;
            float v = acc2[mt][i] + xin[(size_t)m * LBUF + (j + d - pad)];
            xout[(size_t)m * LBUF + j] = v;
          }
      }
      int js = j - off_s;
      if (js >= 0) {
#pragma unroll
        for (int i = 0; i < 4; ++i) {
          int s = lg * 4 + i;
          float v = acc2[2][i];
          if (first) skip[(size_t)s * TF + js] = v;
          else       skip[(size_t)s * TF + js] += v;
        }
      }
    }
  }
}

// Fused final MLP, split-bf16 MFMA: out = W2 @ relu(W1 @ relu(skip)).
// Block: 64 cols, 4 waves (1 n-tile each). H1 split in LDS; W2 chunked K=64.
__global__ __launch_bounds__(256) void k_final(
    const float* __restrict__ skip,
    const float* __restrict__ w1, const float* __restrict__ w2,
    float* __restrict__ out)
{
  __shared__ unsigned short SKh[64][40], SKl[64][40];    // [col][k], k>=16 zero
  __shared__ unsigned short H1h[64][264], H1l[64][264];  // [col][q1]
  __shared__ unsigned short W2ch[256][72], W2cl[256][72];// [q][kk] 64-k chunk

  int tid  = threadIdx.x;
  int jb   = blockIdx.x * 64;
  int lane = tid & 63, w = tid >> 6;
  int lr   = lane & 15, lg = lane >> 4;
  int col  = w * 16 + lr;

  for (int i = tid; i < 1024; i += 256) {
    int c = i & 63, k2 = i >> 6;          // k2 0..15 -> k pair (2k2, 2k2+1)
    float v0 = (2 * k2 < 16)     ? fmaxf(skip[(size_t)(2 * k2) * TF + jb + c], 0.f) : 0.f;
    float v1 = (2 * k2 + 1 < 16) ? fmaxf(skip[(size_t)(2 * k2 + 1) * TF + jb + c], 0.f) : 0.f;
    unsigned short l0, l1;
    unsigned ph = pack2(v0, v1, &l0, &l1);
    *(unsigned*)&SKh[c][2 * k2] = ph;
    *(unsigned*)&SKl[c][2 * k2] = (unsigned)l0 | ((unsigned)l1 << 16);
  }
  __syncthreads();

  // GEMM1: h1[256][col] wave-local; W1 from global (L2-hot), split in regs
  {
    bf16x8 bh = *(const bf16x8*)((const char*)&SKh[0][0] + col * 80 + lg * 16);
    bf16x8 bl = *(const bf16x8*)((const char*)&SKl[0][0] + col * 80 + lg * 16);
#pragma unroll 4
    for (int mt = 0; mt < 16; ++mt) {
      bf16x8 ah = {0, 0, 0, 0, 0, 0, 0, 0};
      bf16x8 al = {0, 0, 0, 0, 0, 0, 0, 0};
      if (lg < 2) {   // k = lg*8 + j < 16 valid
        int m = mt * 16 + lr;
#pragma unroll
        for (int j = 0; j < 8; ++j) {
          float f = w1[m * 16 + lg * 8 + j];
          unsigned short h = b16(f);
          ah[j] = (short)h;
          al[j] = (short)b16(f - bf2f(h));
        }
      }
      f32x4 z = {0.f, 0.f, 0.f, 0.f};
      z = __builtin_amdgcn_mfma_f32_16x16x32_bf16(ah, bh, z, 0, 0, 0);
      z = __builtin_amdgcn_mfma_f32_16x16x32_bf16(ah, bl, z, 0, 0, 0);
      z = __builtin_amdgcn_mfma_f32_16x16x32_bf16(al, bh, z, 0, 0, 0);
      int q0 = mt * 16 + lg * 4;
      unsigned short l0, l1, l2, l3;
      unsigned p01 = pack2(fmaxf(z[0], 0.f), fmaxf(z[1], 0.f), &l0, &l1);
      unsigned p23 = pack2(fmaxf(z[2], 0.f), fmaxf(z[3], 0.f), &l2, &l3);
      *(unsigned*)&H1h[col][q0]     = p01;
      *(unsigned*)&H1h[col][q0 + 2] = p23;
      *(unsigned*)&H1l[col][q0]     = (unsigned)l0 | ((unsigned)l1 << 16);
      *(unsigned*)&H1l[col][q0 + 2] = (unsigned)l2 | ((unsigned)l3 << 16);
    }
  }
  // H1 is wave-local (each wave reads only its own 16 cols) -> no barrier needed

  f32x4 acco[16];
#pragma unroll
  for (int mt = 0; mt < 16; ++mt) acco[mt] = (f32x4){0.f, 0.f, 0.f, 0.f};

  for (int kb = 0; kb < 4; ++kb) {
    __syncthreads();   // previous chunk's reads done before overwrite
    for (int i = tid; i < 8192; i += 256) {
      int q = i >> 5, kk2 = i & 31;
      float v0 = w2[q * 256 + kb * 64 + 2 * kk2];
      float v1 = w2[q * 256 + kb * 64 + 2 * kk2 + 1];
      unsigned short l0, l1;
      unsigned ph = pack2(v0, v1, &l0, &l1);
      *(unsigned*)&W2ch[q][2 * kk2] = ph;
      *(unsigned*)&W2cl[q][2 * kk2] = (unsigned)l0 | ((unsigned)l1 << 16);
    }
    __syncthreads();
#pragma unroll
    for (int ks = 0; ks < 2; ++ks) {
      bf16x8 bh = *(const bf16x8*)((const char*)&H1h[0][0] + col * 528 + kb * 128 + ks * 64 + lg * 16);
      bf16x8 bl = *(const bf16x8*)((const char*)&H1l[0][0] + col * 528 + kb * 128 + ks * 64 + lg * 16);
#pragma unroll 4
      for (int mt = 0; mt < 16; ++mt) {
        const char* ab = (const char*)&W2ch[0][0] + (mt * 16 + lr) * 144 + ks * 64 + lg * 16;
        const char* albp = (const char*)&W2cl[0][0] + (mt * 16 + lr) * 144 + ks * 64 + lg * 16;
        bf16x8 ah = *(const bf16x8*)ab;
        bf16x8 al = *(const bf16x8*)albp;
        acco[mt] = __builtin_amdgcn_mfma_f32_16x16x32_bf16(ah, bh, acco[mt], 0, 0, 0);
        acco[mt] = __builtin_amdgcn_mfma_f32_16x16x32_bf16(ah, bl, acco[mt], 0, 0, 0);
        acco[mt] = __builtin_amdgcn_mfma_f32_16x16x32_bf16(al, bh, acco[mt], 0, 0, 0);
      }
    }
  }

#pragma unroll
  for (int mt = 0; mt < 16; ++mt)
#pragma unroll
    for (int i = 0; i < 4; ++i) {
      int q = mt * 16 + lg * 4 + i;
      out[(size_t)q * TF + jb + col] = acco[mt][i];
    }
}

extern "C" void kernel_launch(void* const* d_in, const int* in_sizes, int n_in,
                              void* d_out, int out_size, void* d_ws, size_t ws_size,
                              hipStream_t stream) {
  const float* x_in     = (const float*)d_in[0];
  const float* w_init   = (const float*)d_in[1];
  const float* w_filter = (const float*)d_in[2];
  const float* w_gate   = (const float*)d_in[3];
  const float* w_res    = (const float*)d_in[4];
  const float* w_skip   = (const float*)d_in[5];
  const float* w_f1     = (const float*)d_in[6];
  const float* w_f2     = (const float*)d_in[7];
  float* out = (float*)d_out;

  float* xa    = (float*)d_ws;            // 32 x 131072 fp32
  float* xb    = xa + 32 * (size_t)LBUF;
  float* skipb = xb + 32 * (size_t)LBUF;  // 16 x 130048 fp32

  k_init<<<(LBUF + 255) / 256, 256, 0, stream>>>(x_in, w_init, xa);

  int T = LBUF;
  for (int idx = 0; idx < 20; ++idx) {
    int d    = 1 << (idx % 10);
    int pad  = (d - (T % d)) % d;
    int Tn   = T + pad - d;
    int offs = Tn - TF;
    k_layer<<<(Tn + TB - 1) / TB, 256, 0, stream>>>(
        xa, xb, skipb,
        w_filter + (size_t)idx * 2048, w_gate + (size_t)idx * 2048,
        w_res + (size_t)idx * 1024, w_skip + (size_t)idx * 512,
        Tn, T, d, pad, offs, (idx == 0) ? 1 : 0, (idx == 19) ? 0 : 1);
    float* t = xa; xa = xb; xb = t;
    T = Tn;
  }

  k_final<<<TF / 64, 256, 0, stream>>>(skipb, w_f1, w_f2, out);
}

// Round 7
// 1366.792 us; speedup vs baseline: 1.4877x; 1.0204x over previous
//
#include <hip/hip_runtime.h>

#define LBUF 131072   // channel stride of x buffers
#define TF   130048   // final time length (= 2032 * 64)
#define TB   64       // time-tile per block in k_layer

typedef short bf16x8 __attribute__((ext_vector_type(8)));
typedef float f32x4  __attribute__((ext_vector_type(4)));

__device__ __forceinline__ float ftanh(float x) {
  float ax = fminf(fabsf(x), 15.0f);
  float t  = __expf(2.0f * ax);
  float r  = 1.0f - 2.0f / (t + 1.0f);
  return copysignf(r, x);
}
__device__ __forceinline__ unsigned short b16(float f) {
  unsigned u = __builtin_bit_cast(unsigned, f);
  return (unsigned short)((u + 0x7fffu + ((u >> 16) & 1u)) >> 16);
}
__device__ __forceinline__ float bf2f(unsigned short h) {
  return __builtin_bit_cast(float, ((unsigned)h) << 16);
}
__device__ __forceinline__ unsigned pack2(float v0, float v1,
                                          unsigned short* lo0, unsigned short* lo1) {
  unsigned short h0 = b16(v0), h1 = b16(v1);
  *lo0 = b16(v0 - bf2f(h0));
  *lo1 = b16(v1 - bf2f(h1));
  return (unsigned)h0 | ((unsigned)h1 << 16);
}

__global__ void k_init(const float* __restrict__ in, const float* __restrict__ w_init,
                       float* __restrict__ x) {
  int j = blockIdx.x * blockDim.x + threadIdx.x;
  if (j >= LBUF) return;
  float v = in[j];
#pragma unroll
  for (int c = 0; c < 32; ++c) x[c * LBUF + j] = w_init[c] * v;
}

// One dilated layer, split-bf16 MFMA; epilogue via LDS transpose -> full-line stores.
__global__ __launch_bounds__(256) void k_layer(
    const float* __restrict__ xin, float* __restrict__ xout,
    float* __restrict__ skip,
    const float* __restrict__ wf, const float* __restrict__ wg,
    const float* __restrict__ wr, const float* __restrict__ wsk,
    int Tn, int Told, int d, int pad, int off_s, int first, int writex)
{
  __shared__ unsigned short Xh[TB][72], Xl[TB][72];   // [col][k]
  __shared__ unsigned short Gh[TB][40], Gl[TB][40];   // [col][o]
  __shared__ alignas(16) char regC[18432];            // Wh|Wl, later OutS
  __shared__ unsigned short W2h[48][40], W2l[48][40]; // [m'][o]

  unsigned short (*Wh)[72] = (unsigned short (*)[72])&regC[0];
  unsigned short (*Wl)[72] = (unsigned short (*)[72])&regC[9216];
  float (*OutS)[66] = (float (*)[66])&regC[0];        // [48 rows][64 cols]

  int tid = threadIdx.x;
  int jb  = blockIdx.x * TB;

  for (int i = tid; i < 2048; i += 256) {
    int m = i >> 5, k2 = i & 31;
    const float* src = (m < 32) ? (wf + m * 64) : (wg + (m - 32) * 64);
    unsigned short l0, l1;
    unsigned ph = pack2(src[2 * k2], src[2 * k2 + 1], &l0, &l1);
    *(unsigned*)&Wh[m][2 * k2] = ph;
    *(unsigned*)&Wl[m][2 * k2] = (unsigned)l0 | ((unsigned)l1 << 16);
  }
  for (int i = tid; i < 768; i += 256) {
    int m = i >> 4, o2 = i & 15;
    const float* src = (m < 32) ? (wr + m * 32) : (wsk + (m - 32) * 32);
    unsigned short l0, l1;
    unsigned ph = pack2(src[2 * o2], src[2 * o2 + 1], &l0, &l1);
    *(unsigned*)&W2h[m][2 * o2] = ph;
    *(unsigned*)&W2l[m][2 * o2] = (unsigned)l0 | ((unsigned)l1 << 16);
  }
  for (int i = tid; i < 32 * TB; i += 256) {
    int col = i & (TB - 1), c = i >> 6;
    int e0 = jb + col - pad;
    int e1 = e0 + d;
    float v0 = (e0 >= 0 && e0 < Told) ? xin[(size_t)c * LBUF + e0] : 0.0f;
    float v1 = (e1 >= 0 && e1 < Told) ? xin[(size_t)c * LBUF + e1] : 0.0f;
    unsigned short l0, l1;
    unsigned ph = pack2(v0, v1, &l0, &l1);
    *(unsigned*)&Xh[col][2 * c] = ph;
    *(unsigned*)&Xl[col][2 * c] = (unsigned)l0 | ((unsigned)l1 << 16);
  }
  __syncthreads();

  int lane = tid & 63, w = tid >> 6;
  int lr = lane & 15;
  int lg = lane >> 4;

  // ---- GEMM1: K=64, 3-term split ----
  f32x4 acc1[4];
#pragma unroll
  for (int mt = 0; mt < 4; ++mt) acc1[mt] = (f32x4){0.f, 0.f, 0.f, 0.f};

#pragma unroll
  for (int ks = 0; ks < 2; ++ks) {
    const char* xb = (const char*)&Xh[0][0] + (w * 16 + lr) * 144 + ks * 64 + lg * 16;
    const char* xl = (const char*)&Xl[0][0] + (w * 16 + lr) * 144 + ks * 64 + lg * 16;
    bf16x8 bh = *(const bf16x8*)xb;
    bf16x8 bl = *(const bf16x8*)xl;
#pragma unroll
    for (int mt = 0; mt < 4; ++mt) {
      const char* wb  = (const char*)&Wh[0][0] + (mt * 16 + lr) * 144 + ks * 64 + lg * 16;
      const char* wlp = (const char*)&Wl[0][0] + (mt * 16 + lr) * 144 + ks * 64 + lg * 16;
      bf16x8 ah = *(const bf16x8*)wb;
      bf16x8 al = *(const bf16x8*)wlp;
      acc1[mt] = __builtin_amdgcn_mfma_f32_16x16x32_bf16(ah, bh, acc1[mt], 0, 0, 0);
      acc1[mt] = __builtin_amdgcn_mfma_f32_16x16x32_bf16(ah, bl, acc1[mt], 0, 0, 0);
      acc1[mt] = __builtin_amdgcn_mfma_f32_16x16x32_bf16(al, bh, acc1[mt], 0, 0, 0);
    }
  }

  // ---- gate -> Gh/Gl (wave-local cols) ----
  {
    int col = w * 16 + lr;
#pragma unroll
    for (int t = 0; t < 2; ++t) {
      float g0 = ftanh(acc1[t][0]) * ftanh(acc1[t + 2][0]);
      float g1 = ftanh(acc1[t][1]) * ftanh(acc1[t + 2][1]);
      float g2 = ftanh(acc1[t][2]) * ftanh(acc1[t + 2][2]);
      float g3 = ftanh(acc1[t][3]) * ftanh(acc1[t + 2][3]);
      int o0 = t * 16 + lg * 4;
      unsigned short l0, l1, l2, l3;
      unsigned p01 = pack2(g0, g1, &l0, &l1);
      unsigned p23 = pack2(g2, g3, &l2, &l3);
      *(unsigned*)&Gh[col][o0]     = p01;
      *(unsigned*)&Gh[col][o0 + 2] = p23;
      *(unsigned*)&Gl[col][o0]     = (unsigned)l0 | ((unsigned)l1 << 16);
      *(unsigned*)&Gl[col][o0 + 2] = (unsigned)l2 | ((unsigned)l3 << 16);
    }
  }

  // ---- GEMM2: K=32, 3-term split; wave-local ----
  f32x4 acc2[3];
  {
    const char* gb = (const char*)&Gh[0][0] + (w * 16 + lr) * 80 + lg * 16;
    const char* gl = (const char*)&Gl[0][0] + (w * 16 + lr) * 80 + lg * 16;
    bf16x8 bh = *(const bf16x8*)gb;
    bf16x8 bl = *(const bf16x8*)gl;
#pragma unroll
    for (int mt = 0; mt < 3; ++mt) {
      const char* ab   = (const char*)&W2h[0][0] + (mt * 16 + lr) * 80 + lg * 16;
      const char* albp = (const char*)&W2l[0][0] + (mt * 16 + lr) * 80 + lg * 16;
      bf16x8 ah = *(const bf16x8*)ab;
      bf16x8 al = *(const bf16x8*)albp;
      f32x4 z = {0.f, 0.f, 0.f, 0.f};
      z = __builtin_amdgcn_mfma_f32_16x16x32_bf16(ah, bh, z, 0, 0, 0);
      z = __builtin_amdgcn_mfma_f32_16x16x32_bf16(ah, bl, z, 0, 0, 0);
      acc2[mt] = __builtin_amdgcn_mfma_f32_16x16x32_bf16(al, bh, z, 0, 0, 0);
    }
  }

  __syncthreads();   // everyone done reading Wh/Wl (and all GEMM LDS)
  // ---- OutS transpose write ----
  {
    int col = w * 16 + lr;
#pragma unroll
    for (int mt = 0; mt < 2; ++mt)
#pragma unroll
      for (int i = 0; i < 4; ++i) {
        int m = mt * 16 + lg * 4 + i;
        float xr = bf2f(Xh[col][2 * m + 1]) + bf2f(Xl[col][2 * m + 1]);
        OutS[m][col] = acc2[mt][i] + xr;
      }
#pragma unroll
    for (int i = 0; i < 4; ++i)
      OutS[32 + lg * 4 + i][col] = acc2[2][i];
  }
  __syncthreads();

  // ---- coalesced coop stores (64-lane contiguous = full lines) ----
  int c  = tid & 63, wv = tid >> 6;
  int j  = jb + c;
  if (writex && j < Tn) {
#pragma unroll 4
    for (int r = wv; r < 32; r += 4)
      xout[(size_t)r * LBUF + j] = OutS[r][c];
  }
  int js = j - off_s;
  if (j < Tn && js >= 0) {
    if (first) {
#pragma unroll
      for (int r = wv; r < 16; r += 4)
        skip[(size_t)r * TF + js] = OutS[32 + r][c];
    } else {
#pragma unroll
      for (int r = wv; r < 16; r += 4)
        skip[(size_t)r * TF + js] += OutS[32 + r][c];
    }
  }
}

// h1 = relu(W1 @ relu(skip)) -> packed (hi|lo<<16) u32 plane [256][TF]
__global__ __launch_bounds__(256) void k_h1(
    const float* __restrict__ skip, const float* __restrict__ w1,
    unsigned* __restrict__ h1p)
{
  __shared__ unsigned short SKh[64][40], SKl[64][40];
  __shared__ unsigned Hs[256][66];

  int tid  = threadIdx.x;
  int jb   = blockIdx.x * 64;
  int lane = tid & 63, w = tid >> 6;
  int lr   = lane & 15, lg = lane >> 4;
  int col  = w * 16 + lr;

  for (int i = tid; i < 1024; i += 256) {
    int c = i & 63, k2 = i >> 6;
    float v0 = (2 * k2 < 16)     ? fmaxf(skip[(size_t)(2 * k2) * TF + jb + c], 0.f) : 0.f;
    float v1 = (2 * k2 + 1 < 16) ? fmaxf(skip[(size_t)(2 * k2 + 1) * TF + jb + c], 0.f) : 0.f;
    unsigned short l0, l1;
    unsigned ph = pack2(v0, v1, &l0, &l1);
    *(unsigned*)&SKh[c][2 * k2] = ph;
    *(unsigned*)&SKl[c][2 * k2] = (unsigned)l0 | ((unsigned)l1 << 16);
  }
  __syncthreads();

  bf16x8 bh = *(const bf16x8*)((const char*)&SKh[0][0] + col * 80 + lg * 16);
  bf16x8 bl = *(const bf16x8*)((const char*)&SKl[0][0] + col * 80 + lg * 16);
#pragma unroll 4
  for (int mt = 0; mt < 16; ++mt) {
    bf16x8 ah = {0, 0, 0, 0, 0, 0, 0, 0};
    bf16x8 al = {0, 0, 0, 0, 0, 0, 0, 0};
    if (lg < 2) {
      int m = mt * 16 + lr;
#pragma unroll
      for (int jj = 0; jj < 8; ++jj) {
        float f = w1[m * 16 + lg * 8 + jj];
        unsigned short h = b16(f);
        ah[jj] = (short)h;
        al[jj] = (short)b16(f - bf2f(h));
      }
    }
    f32x4 z = {0.f, 0.f, 0.f, 0.f};
    z = __builtin_amdgcn_mfma_f32_16x16x32_bf16(ah, bh, z, 0, 0, 0);
    z = __builtin_amdgcn_mfma_f32_16x16x32_bf16(ah, bl, z, 0, 0, 0);
    z = __builtin_amdgcn_mfma_f32_16x16x32_bf16(al, bh, z, 0, 0, 0);
#pragma unroll
    for (int i = 0; i < 4; ++i) {
      float v = fmaxf(z[i], 0.f);
      unsigned short h = b16(v);
      unsigned short l = b16(v - bf2f(h));
      Hs[mt * 16 + lg * 4 + i][col] = (unsigned)h | ((unsigned)l << 16);
    }
  }
  __syncthreads();

  int c = tid & 63, wv = tid >> 6;
#pragma unroll 8
  for (int r = wv; r < 256; r += 4)
    h1p[(size_t)r * TF + jb + c] = Hs[r][c];
}

// out = W2 @ h1 (split 3-term), K=256 chunked by 32. Block: 256q x 128 cols, 4 waves.
// h1p aliases d_out: every block reads all rows of its cols before writing them.
__global__ __launch_bounds__(256) void k_out(
    const unsigned* __restrict__ h1p, const float* __restrict__ w2,
    float* __restrict__ out)
{
  __shared__ alignas(16) char smem[67584];
  unsigned short (*W2ch)[40] = (unsigned short (*)[40])&smem[0];      // 20480
  unsigned short (*W2cl)[40] = (unsigned short (*)[40])&smem[20480];  // 20480
  unsigned short (*Hch)[40]  = (unsigned short (*)[40])&smem[40960];  // [128 col][32k] 10240
  unsigned short (*Hcl)[40]  = (unsigned short (*)[40])&smem[51200];  // 10240
  float (*OutS)[66] = (float (*)[66])&smem[0];                         // [256][64] 67584

  int tid  = threadIdx.x;
  int jb   = blockIdx.x * 128;
  int lane = tid & 63, w = tid >> 6;
  int lr   = lane & 15, lg = lane >> 4;

  f32x4 acc[2][16];
#pragma unroll
  for (int nt = 0; nt < 2; ++nt)
#pragma unroll
    for (int mt = 0; mt < 16; ++mt) acc[nt][mt] = (f32x4){0.f, 0.f, 0.f, 0.f};

  for (int kb = 0; kb < 8; ++kb) {
    __syncthreads();
    // stage W2 chunk [256 q][32 k] split
    for (int i = tid; i < 4096; i += 256) {
      int q = i >> 4, k2 = i & 15;
      unsigned short l0, l1;
      unsigned ph = pack2(w2[q * 256 + kb * 32 + 2 * k2],
                          w2[q * 256 + kb * 32 + 2 * k2 + 1], &l0, &l1);
      *(unsigned*)&W2ch[q][2 * k2] = ph;
      *(unsigned*)&W2cl[q][2 * k2] = (unsigned)l0 | ((unsigned)l1 << 16);
    }
    // stage H chunk: rows k=kb*32..+31, cols jb..jb+127 (coalesced u32 reads)
    for (int i = tid; i < 4096; i += 256) {
      int k = i >> 7, c = i & 127;
      unsigned p = h1p[(size_t)(kb * 32 + k) * TF + jb + c];
      Hch[c][k] = (unsigned short)(p & 0xffffu);
      Hcl[c][k] = (unsigned short)(p >> 16);
    }
    __syncthreads();

#pragma unroll
    for (int nt = 0; nt < 2; ++nt) {
      int col = w * 32 + nt * 16 + lr;
      bf16x8 bh = *(const bf16x8*)((const char*)&Hch[0][0] + col * 80 + lg * 16);
      bf16x8 bl = *(const bf16x8*)((const char*)&Hcl[0][0] + col * 80 + lg * 16);
#pragma unroll 4
      for (int mt = 0; mt < 16; ++mt) {
        const char* ab = (const char*)&W2ch[0][0] + (mt * 16 + lr) * 80 + lg * 16;
        const char* al_ = (const char*)&W2cl[0][0] + (mt * 16 + lr) * 80 + lg * 16;
        bf16x8 ah = *(const bf16x8*)ab;
        bf16x8 al = *(const bf16x8*)al_;
        acc[nt][mt] = __builtin_amdgcn_mfma_f32_16x16x32_bf16(ah, bh, acc[nt][mt], 0, 0, 0);
        acc[nt][mt] = __builtin_amdgcn_mfma_f32_16x16x32_bf16(ah, bl, acc[nt][mt], 0, 0, 0);
        acc[nt][mt] = __builtin_amdgcn_mfma_f32_16x16x32_bf16(al, bh, acc[nt][mt], 0, 0, 0);
      }
    }
  }
  __syncthreads();

  // epilogue: two 64-col halves through OutS, full-line coop stores
#pragma unroll
  for (int half = 0; half < 2; ++half) {
    if ((w >> 1) == half) {
#pragma unroll
      for (int nt = 0; nt < 2; ++nt) {
        int col_l = (w & 1) * 32 + nt * 16 + lr;
#pragma unroll
        for (int mt = 0; mt < 16; ++mt)
#pragma unroll
          for (int i = 0; i < 4; ++i)
            OutS[mt * 16 + lg * 4 + i][col_l] = acc[nt][mt][i];
      }
    }
    __syncthreads();
    int c = tid & 63, wv = tid >> 6;
    size_t base = (size_t)jb + half * 64 + c;
#pragma unroll 4
    for (int r = wv; r < 256; r += 4)
      out[(size_t)r * TF + base] = OutS[r][c];
    __syncthreads();
  }
}

extern "C" void kernel_launch(void* const* d_in, const int* in_sizes, int n_in,
                              void* d_out, int out_size, void* d_ws, size_t ws_size,
                              hipStream_t stream) {
  const float* x_in     = (const float*)d_in[0];
  const float* w_init   = (const float*)d_in[1];
  const float* w_filter = (const float*)d_in[2];
  const float* w_gate   = (const float*)d_in[3];
  const float* w_res    = (const float*)d_in[4];
  const float* w_skip   = (const float*)d_in[5];
  const float* w_f1     = (const float*)d_in[6];
  const float* w_f2     = (const float*)d_in[7];
  float* out = (float*)d_out;

  float* xa    = (float*)d_ws;            // 32 x 131072 fp32
  float* xb    = xa + 32 * (size_t)LBUF;
  float* skipb = xb + 32 * (size_t)LBUF;  // 16 x 130048 fp32
  unsigned* h1p = (unsigned*)d_out;       // packed h1 aliases the output buffer

  k_init<<<(LBUF + 255) / 256, 256, 0, stream>>>(x_in, w_init, xa);

  int T = LBUF;
  for (int idx = 0; idx < 20; ++idx) {
    int d    = 1 << (idx % 10);
    int pad  = (d - (T % d)) % d;
    int Tn   = T + pad - d;
    int offs = Tn - TF;
    k_layer<<<(Tn + TB - 1) / TB, 256, 0, stream>>>(
        xa, xb, skipb,
        w_filter + (size_t)idx * 2048, w_gate + (size_t)idx * 2048,
        w_res + (size_t)idx * 1024, w_skip + (size_t)idx * 512,
        Tn, T, d, pad, offs, (idx == 0) ? 1 : 0, (idx == 19) ? 0 : 1);
    float* t = xa; xa = xb; xb = t;
    T = Tn;
  }

  k_h1 <<<TF / 64, 256, 0, stream>>>(skipb, w_f1, h1p);
  k_out<<<TF / 128, 256, 0, stream>>>(h1p, w_f2, out);
}

// Round 8
// 1056.950 us; speedup vs baseline: 1.9238x; 1.2931x over previous
//
#include <hip/hip_runtime.h>

#define LBUF 131072
#define TF   130048
#define TB   64

typedef short bf16x8 __attribute__((ext_vector_type(8)));
typedef float f32x4  __attribute__((ext_vector_type(4)));

__device__ __forceinline__ float ftanh(float x) {
  float ax = fminf(fabsf(x), 15.0f);
  float t  = __expf(2.0f * ax);
  float r  = 1.0f - 2.0f / (t + 1.0f);
  return copysignf(r, x);
}
__device__ __forceinline__ unsigned short b16(float f) {
  unsigned u = __builtin_bit_cast(unsigned, f);
  return (unsigned short)((u + 0x7fffu + ((u >> 16) & 1u)) >> 16);
}
__device__ __forceinline__ float bf2f(unsigned short h) {
  return __builtin_bit_cast(float, ((unsigned)h) << 16);
}
__device__ __forceinline__ unsigned pack2(float v0, float v1,
                                          unsigned short* lo0, unsigned short* lo1) {
  unsigned short h0 = b16(v0), h1 = b16(v1);
  *lo0 = b16(v0 - bf2f(h0));
  *lo1 = b16(v1 - bf2f(h1));
  return (unsigned)h0 | ((unsigned)h1 << 16);
}

__global__ void k_init(const float* __restrict__ in, const float* __restrict__ w_init,
                       float* __restrict__ x) {
  int t = blockIdx.x * blockDim.x + threadIdx.x;
  int j = t * 4;
  if (j >= LBUF) return;
  float4 v = *(const float4*)&in[j];
#pragma unroll
  for (int c = 0; c < 32; ++c) {
    float s = w_init[c];
    float4 o = {s * v.x, s * v.y, s * v.z, s * v.w};
    *(float4*)&x[(size_t)c * LBUF + j] = o;
  }
}

// One dilated layer, split-bf16 MFMA; W2 in regs; epilogue = LDS transpose + float4 stores.
__global__ __launch_bounds__(256) void k_layer(
    const float* __restrict__ xin, float* __restrict__ xout,
    float* __restrict__ skip,
    const float* __restrict__ wf, const float* __restrict__ wg,
    const float* __restrict__ wr, const float* __restrict__ wsk,
    int Tn, int Told, int d, int pad, int off_s, int first, int writex)
{
  __shared__ unsigned short Xh[TB][72], Xl[TB][72];   // [col][k=2c+tap]
  __shared__ unsigned short Gh[TB][40], Gl[TB][40];   // [col][o]
  __shared__ alignas(16) char wbuf[18432];            // Wh|Wl, later OutS
  unsigned short (*Wh)[72] = (unsigned short (*)[72])&wbuf[0];
  unsigned short (*Wl)[72] = (unsigned short (*)[72])&wbuf[9216];
  float (*OutS)[68] = (float (*)[68])&wbuf[0];        // 48*272 = 13056 B

  int tid = threadIdx.x;
  int jb  = blockIdx.x * TB;
  int lane = tid & 63, w = tid >> 6;
  int lr = lane & 15, lg = lane >> 4;

  // ---- W2 fragments straight into registers (per-lane; identical across waves -> L2) ----
  bf16x8 a2h[3], a2l[3];
#pragma unroll
  for (int mt = 0; mt < 3; ++mt) {
    int m = mt * 16 + lr;
    const float* src = (m < 32) ? (wr + m * 32) : (wsk + (m - 32) * 32);
    float4 f0 = *(const float4*)&src[lg * 8];
    float4 f1 = *(const float4*)&src[lg * 8 + 4];
    float fv[8] = {f0.x, f0.y, f0.z, f0.w, f1.x, f1.y, f1.z, f1.w};
#pragma unroll
    for (int j = 0; j < 8; ++j) {
      unsigned short h = b16(fv[j]);
      a2h[mt][j] = (short)h;
      a2l[mt][j] = (short)b16(fv[j] - bf2f(h));
    }
  }

  // ---- stage conv weights (4096 vals as hi/lo pairs) ----
  for (int i = tid; i < 2048; i += 256) {
    int m = i >> 5, k2 = i & 31;
    const float* src = (m < 32) ? (wf + m * 64) : (wg + (m - 32) * 64);
    unsigned short l0, l1;
    unsigned ph = pack2(src[2 * k2], src[2 * k2 + 1], &l0, &l1);
    *(unsigned*)&Wh[m][2 * k2] = ph;
    *(unsigned*)&Wl[m][2 * k2] = (unsigned)l0 | ((unsigned)l1 << 16);
  }
  // ---- stage X tile ----
  for (int i = tid; i < 32 * TB; i += 256) {
    int col = i & (TB - 1), c = i >> 6;
    int e0 = jb + col - pad;
    int e1 = e0 + d;
    float v0 = (e0 >= 0 && e0 < Told) ? xin[(size_t)c * LBUF + e0] : 0.0f;
    float v1 = (e1 >= 0 && e1 < Told) ? xin[(size_t)c * LBUF + e1] : 0.0f;
    unsigned short l0, l1;
    unsigned ph = pack2(v0, v1, &l0, &l1);
    *(unsigned*)&Xh[col][2 * c] = ph;
    *(unsigned*)&Xl[col][2 * c] = (unsigned)l0 | ((unsigned)l1 << 16);
  }
  __syncthreads();

  // ---- GEMM1: K=64, 3-term split ----
  f32x4 acc1[4];
#pragma unroll
  for (int mt = 0; mt < 4; ++mt) acc1[mt] = (f32x4){0.f, 0.f, 0.f, 0.f};
#pragma unroll
  for (int ks = 0; ks < 2; ++ks) {
    const char* xb = (const char*)&Xh[0][0] + (w * 16 + lr) * 144 + ks * 64 + lg * 16;
    const char* xl = (const char*)&Xl[0][0] + (w * 16 + lr) * 144 + ks * 64 + lg * 16;
    bf16x8 bh = *(const bf16x8*)xb;
    bf16x8 bl = *(const bf16x8*)xl;
#pragma unroll
    for (int mt = 0; mt < 4; ++mt) {
      const char* wb  = (const char*)&Wh[0][0] + (mt * 16 + lr) * 144 + ks * 64 + lg * 16;
      const char* wlp = (const char*)&Wl[0][0] + (mt * 16 + lr) * 144 + ks * 64 + lg * 16;
      bf16x8 ah = *(const bf16x8*)wb;
      bf16x8 al = *(const bf16x8*)wlp;
      acc1[mt] = __builtin_amdgcn_mfma_f32_16x16x32_bf16(ah, bh, acc1[mt], 0, 0, 0);
      acc1[mt] = __builtin_amdgcn_mfma_f32_16x16x32_bf16(ah, bl, acc1[mt], 0, 0, 0);
      acc1[mt] = __builtin_amdgcn_mfma_f32_16x16x32_bf16(al, bh, acc1[mt], 0, 0, 0);
    }
  }

  // ---- gate -> Gh/Gl (wave-local cols) ----
  {
    int col = w * 16 + lr;
#pragma unroll
    for (int t = 0; t < 2; ++t) {
      float g0 = ftanh(acc1[t][0]) * ftanh(acc1[t + 2][0]);
      float g1 = ftanh(acc1[t][1]) * ftanh(acc1[t + 2][1]);
      float g2 = ftanh(acc1[t][2]) * ftanh(acc1[t + 2][2]);
      float g3 = ftanh(acc1[t][3]) * ftanh(acc1[t + 2][3]);
      int o0 = t * 16 + lg * 4;
      unsigned short l0, l1, l2, l3;
      unsigned p01 = pack2(g0, g1, &l0, &l1);
      unsigned p23 = pack2(g2, g3, &l2, &l3);
      *(unsigned*)&Gh[col][o0]     = p01;
      *(unsigned*)&Gh[col][o0 + 2] = p23;
      *(unsigned*)&Gl[col][o0]     = (unsigned)l0 | ((unsigned)l1 << 16);
      *(unsigned*)&Gl[col][o0 + 2] = (unsigned)l2 | ((unsigned)l3 << 16);
    }
  }

  // ---- GEMM2: K=32, 3-term, A from regs; wave-local B ----
  f32x4 acc2[3];
  {
    const char* gb = (const char*)&Gh[0][0] + (w * 16 + lr) * 80 + lg * 16;
    const char* gl = (const char*)&Gl[0][0] + (w * 16 + lr) * 80 + lg * 16;
    bf16x8 bh = *(const bf16x8*)gb;
    bf16x8 bl = *(const bf16x8*)gl;
#pragma unroll
    for (int mt = 0; mt < 3; ++mt) {
      f32x4 z = {0.f, 0.f, 0.f, 0.f};
      z = __builtin_amdgcn_mfma_f32_16x16x32_bf16(a2h[mt], bh, z, 0, 0, 0);
      z = __builtin_amdgcn_mfma_f32_16x16x32_bf16(a2h[mt], bl, z, 0, 0, 0);
      acc2[mt] = __builtin_amdgcn_mfma_f32_16x16x32_bf16(a2l[mt], bh, z, 0, 0, 0);
    }
  }

  __syncthreads();   // all GEMM1 reads of Wh/Wl done -> reuse as OutS
  {
    int col = w * 16 + lr;
#pragma unroll
    for (int mt = 0; mt < 2; ++mt)
#pragma unroll
      for (int i = 0; i < 4; ++i) {
        int m = mt * 16 + lg * 4 + i;
        float xr = bf2f(Xh[col][2 * m + 1]) + bf2f(Xl[col][2 * m + 1]);
        OutS[m][col] = acc2[mt][i] + xr;
      }
#pragma unroll
    for (int i = 0; i < 4; ++i)
      OutS[32 + lg * 4 + i][col] = acc2[2][i];
  }
  __syncthreads();

  bool fullN = (jb + TB <= Tn);
  if (writex) {
    if (fullN) {
      int r = tid >> 3, cb = (tid & 7) * 8;
      size_t base = (size_t)r * LBUF + jb + cb;
      float4 v0 = *(float4*)&OutS[r][cb];
      float4 v1 = *(float4*)&OutS[r][cb + 4];
      *(float4*)&xout[base]     = v0;
      *(float4*)&xout[base + 4] = v1;
    } else {
      int c = tid & 63, r0 = tid >> 6;
      int j = jb + c;
      if (j < Tn)
#pragma unroll
        for (int rr = r0; rr < 32; rr += 4)
          xout[(size_t)rr * LBUF + j] = OutS[rr][c];
    }
  }
  if (fullN && ((off_s & 3) == 0) && jb >= off_s) {
    int r = tid >> 4, cb = (tid & 15) * 4;
    size_t base = (size_t)r * TF + (jb - off_s) + cb;
    float4 v = *(float4*)&OutS[32 + r][cb];
    if (first) {
      *(float4*)&skip[base] = v;
    } else {
      float4 o = *(const float4*)&skip[base];
      o.x += v.x; o.y += v.y; o.z += v.z; o.w += v.w;
      *(float4*)&skip[base] = o;
    }
  } else {
    int c = tid & 63, r0 = tid >> 6;
    int j = jb + c, js = j - off_s;
    if (j < Tn && js >= 0) {
#pragma unroll
      for (int rr = r0; rr < 16; rr += 4) {
        if (first) skip[(size_t)rr * TF + js]  = OutS[32 + rr][c];
        else       skip[(size_t)rr * TF + js] += OutS[32 + rr][c];
      }
    }
  }
}

// Fused final MLP: out = W2 @ relu(W1 @ relu(skip)). H1 bf16 in LDS; W2 split chunks.
__global__ __launch_bounds__(256) void k_final(
    const float* __restrict__ skip,
    const float* __restrict__ w1, const float* __restrict__ w2,
    float* __restrict__ out)
{
  __shared__ alignas(16) char smem[74752];
  unsigned short (*H1)[264]  = (unsigned short (*)[264])&smem[0];      // 33792
  unsigned short (*SKh)[40]  = (unsigned short (*)[40])&smem[33792];   // 5120
  unsigned short (*SKl)[40]  = (unsigned short (*)[40])&smem[38912];   // 5120
  unsigned short (*W2ch)[40] = (unsigned short (*)[40])&smem[33792];   // 20480
  unsigned short (*W2cl)[40] = (unsigned short (*)[40])&smem[54272];   // 20480
  float (*OutS)[68] = (float (*)[68])&smem[0];                          // 69632

  int tid = threadIdx.x;
  int jb  = blockIdx.x * 64;
  int lane = tid & 63, w = tid >> 6;
  int lr = lane & 15, lg = lane >> 4;
  int col = w * 16 + lr;

  for (int i = tid; i < 1024; i += 256) {
    int c = i & 63, k2 = i >> 6;
    float v0 = (2 * k2 < 16)     ? fmaxf(skip[(size_t)(2 * k2) * TF + jb + c], 0.f) : 0.f;
    float v1 = (2 * k2 + 1 < 16) ? fmaxf(skip[(size_t)(2 * k2 + 1) * TF + jb + c], 0.f) : 0.f;
    unsigned short l0, l1;
    unsigned ph = pack2(v0, v1, &l0, &l1);
    *(unsigned*)&SKh[c][2 * k2] = ph;
    *(unsigned*)&SKl[c][2 * k2] = (unsigned)l0 | ((unsigned)l1 << 16);
  }
  __syncthreads();

  // GEMM1: 3-term split; h1 -> H1 bf16 (wave-local cols)
  {
    bf16x8 bh = *(const bf16x8*)((const char*)&SKh[0][0] + col * 80 + lg * 16);
    bf16x8 bl = *(const bf16x8*)((const char*)&SKl[0][0] + col * 80 + lg * 16);
#pragma unroll 4
    for (int mt = 0; mt < 16; ++mt) {
      bf16x8 ah = {0, 0, 0, 0, 0, 0, 0, 0};
      bf16x8 al = {0, 0, 0, 0, 0, 0, 0, 0};
      if (lg < 2) {
        int m = mt * 16 + lr;
#pragma unroll
        for (int jj = 0; jj < 8; ++jj) {
          float f = w1[m * 16 + lg * 8 + jj];
          unsigned short h = b16(f);
          ah[jj] = (short)h;
          al[jj] = (short)b16(f - bf2f(h));
        }
      }
      f32x4 z = {0.f, 0.f, 0.f, 0.f};
      z = __builtin_amdgcn_mfma_f32_16x16x32_bf16(ah, bh, z, 0, 0, 0);
      z = __builtin_amdgcn_mfma_f32_16x16x32_bf16(ah, bl, z, 0, 0, 0);
      z = __builtin_amdgcn_mfma_f32_16x16x32_bf16(al, bh, z, 0, 0, 0);
      int q0 = mt * 16 + lg * 4;
      unsigned p01 = (unsigned)b16(fmaxf(z[0], 0.f)) | ((unsigned)b16(fmaxf(z[1], 0.f)) << 16);
      unsigned p23 = (unsigned)b16(fmaxf(z[2], 0.f)) | ((unsigned)b16(fmaxf(z[3], 0.f)) << 16);
      *(unsigned*)&H1[col][q0]     = p01;
      *(unsigned*)&H1[col][q0 + 2] = p23;
    }
  }

  f32x4 acco[16];
#pragma unroll
  for (int mt = 0; mt < 16; ++mt) acco[mt] = (f32x4){0.f, 0.f, 0.f, 0.f};

  for (int kb = 0; kb < 8; ++kb) {
    __syncthreads();  // iter0: GEMM1 done before SK overwritten; else: prev reads done
    for (int i = tid; i < 4096; i += 256) {
      int q = i >> 4, k2 = i & 15;
      unsigned short l0, l1;
      unsigned ph = pack2(w2[q * 256 + kb * 32 + 2 * k2],
                          w2[q * 256 + kb * 32 + 2 * k2 + 1], &l0, &l1);
      *(unsigned*)&W2ch[q][2 * k2] = ph;
      *(unsigned*)&W2cl[q][2 * k2] = (unsigned)l0 | ((unsigned)l1 << 16);
    }
    __syncthreads();
    bf16x8 bh = *(const bf16x8*)((const char*)&H1[0][0] + col * 528 + kb * 64 + lg * 16);
#pragma unroll 4
    for (int mt = 0; mt < 16; ++mt) {
      bf16x8 ah = *(const bf16x8*)((const char*)&W2ch[0][0] + (mt * 16 + lr) * 80 + lg * 16);
      bf16x8 al = *(const bf16x8*)((const char*)&W2cl[0][0] + (mt * 16 + lr) * 80 + lg * 16);
      acco[mt] = __builtin_amdgcn_mfma_f32_16x16x32_bf16(ah, bh, acco[mt], 0, 0, 0);
      acco[mt] = __builtin_amdgcn_mfma_f32_16x16x32_bf16(al, bh, acco[mt], 0, 0, 0);
    }
  }

  __syncthreads();
#pragma unroll
  for (int mt = 0; mt < 16; ++mt)
#pragma unroll
    for (int i = 0; i < 4; ++i)
      OutS[mt * 16 + lg * 4 + i][col] = acco[mt][i];
  __syncthreads();

  int ty = tid >> 3, tx = tid & 7;
#pragma unroll
  for (int i = 0; i < 8; ++i) {
    int q = ty * 8 + i;
    float4 v0 = *(float4*)&OutS[q][tx * 8];
    float4 v1 = *(float4*)&OutS[q][tx * 8 + 4];
    size_t base = (size_t)q * TF + jb + tx * 8;
    *(float4*)&out[base]     = v0;
    *(float4*)&out[base + 4] = v1;
  }
}

extern "C" void kernel_launch(void* const* d_in, const int* in_sizes, int n_in,
                              void* d_out, int out_size, void* d_ws, size_t ws_size,
                              hipStream_t stream) {
  const float* x_in     = (const float*)d_in[0];
  const float* w_init   = (const float*)d_in[1];
  const float* w_filter = (const float*)d_in[2];
  const float* w_gate   = (const float*)d_in[3];
  const float* w_res    = (const float*)d_in[4];
  const float* w_skip   = (const float*)d_in[5];
  const float* w_f1     = (const float*)d_in[6];
  const float* w_f2     = (const float*)d_in[7];
  float* out = (float*)d_out;

  float* xa    = (float*)d_ws;
  float* xb    = xa + 32 * (size_t)LBUF;
  float* skipb = xb + 32 * (size_t)LBUF;

  k_init<<<LBUF / 1024, 256, 0, stream>>>(x_in, w_init, xa);

  int T = LBUF;
  for (int idx = 0; idx < 20; ++idx) {
    int d    = 1 << (idx % 10);
    int pad  = (d - (T % d)) % d;
    int Tn   = T + pad - d;
    int offs = Tn - TF;
    k_layer<<<(Tn + TB - 1) / TB, 256, 0, stream>>>(
        xa, xb, skipb,
        w_filter + (size_t)idx * 2048, w_gate + (size_t)idx * 2048,
        w_res + (size_t)idx * 1024, w_skip + (size_t)idx * 512,
        Tn, T, d, pad, offs, (idx == 0) ? 1 : 0, (idx == 19) ? 0 : 1);
    float* t = xa; xa = xb; xb = t;
    T = Tn;
  }

  k_final<<<TF / 64, 256, 0, stream>>>(skipb, w_f1, w_f2, out);
}

// Round 9
// 878.099 us; speedup vs baseline: 2.3156x; 1.2037x over previous
//
#include <hip/hip_runtime.h>

#define LBUF 131072
#define TF   130048
#define TB   64

typedef short bf16x8 __attribute__((ext_vector_type(8)));
typedef float f32x4  __attribute__((ext_vector_type(4)));

__device__ __forceinline__ float ftanh(float x) {
  float ax = fminf(fabsf(x), 15.0f);
  float t  = __expf(2.0f * ax);
  float r  = 1.0f - 2.0f / (t + 1.0f);
  return copysignf(r, x);
}
__device__ __forceinline__ unsigned short b16(float f) {
  unsigned u = __builtin_bit_cast(unsigned, f);
  return (unsigned short)((u + 0x7fffu + ((u >> 16) & 1u)) >> 16);
}
__device__ __forceinline__ float bf2f(unsigned short h) {
  return __builtin_bit_cast(float, ((unsigned)h) << 16);
}
__device__ __forceinline__ unsigned pack2(float v0, float v1,
                                          unsigned short* lo0, unsigned short* lo1) {
  unsigned short h0 = b16(v0), h1 = b16(v1);
  *lo0 = b16(v0 - bf2f(h0));
  *lo1 = b16(v1 - bf2f(h1));
  return (unsigned)h0 | ((unsigned)h1 << 16);
}

__global__ void k_init(const float* __restrict__ in, const float* __restrict__ w_init,
                       float* __restrict__ x) {
  int t = blockIdx.x * blockDim.x + threadIdx.x;
  int j = t * 4;
  if (j >= LBUF) return;
  float4 v = *(const float4*)&in[j];
#pragma unroll
  for (int c = 0; c < 32; ++c) {
    float s = w_init[c];
    float4 o = {s * v.x, s * v.y, s * v.z, s * v.w};
    *(float4*)&x[(size_t)c * LBUF + j] = o;
  }
}

// One dilated layer, split-bf16 MFMA; W2 in regs; epilogue = LDS transpose + float4 stores.
__global__ __launch_bounds__(256) void k_layer(
    const float* __restrict__ xin, float* __restrict__ xout,
    float* __restrict__ skip,
    const float* __restrict__ wf, const float* __restrict__ wg,
    const float* __restrict__ wr, const float* __restrict__ wsk,
    int Tn, int Told, int d, int pad, int off_s, int first, int writex)
{
  __shared__ unsigned short Xh[TB][72], Xl[TB][72];   // [col][k=2c+tap]
  __shared__ unsigned short Gh[TB][40], Gl[TB][40];   // [col][o]
  __shared__ alignas(16) char wbuf[18432];            // Wh|Wl, later OutS
  unsigned short (*Wh)[72] = (unsigned short (*)[72])&wbuf[0];
  unsigned short (*Wl)[72] = (unsigned short (*)[72])&wbuf[9216];
  float (*OutS)[68] = (float (*)[68])&wbuf[0];        // 48*272 = 13056 B

  int tid = threadIdx.x;
  int jb  = blockIdx.x * TB;
  int lane = tid & 63, w = tid >> 6;
  int lr = lane & 15, lg = lane >> 4;

  // ---- W2 fragments straight into registers (per-lane; identical across waves -> L2) ----
  bf16x8 a2h[3], a2l[3];
#pragma unroll
  for (int mt = 0; mt < 3; ++mt) {
    int m = mt * 16 + lr;
    const float* src = (m < 32) ? (wr + m * 32) : (wsk + (m - 32) * 32);
    float4 f0 = *(const float4*)&src[lg * 8];
    float4 f1 = *(const float4*)&src[lg * 8 + 4];
    float fv[8] = {f0.x, f0.y, f0.z, f0.w, f1.x, f1.y, f1.z, f1.w};
#pragma unroll
    for (int j = 0; j < 8; ++j) {
      unsigned short h = b16(fv[j]);
      a2h[mt][j] = (short)h;
      a2l[mt][j] = (short)b16(fv[j] - bf2f(h));
    }
  }

  // ---- stage conv weights (4096 vals as hi/lo pairs) ----
  for (int i = tid; i < 2048; i += 256) {
    int m = i >> 5, k2 = i & 31;
    const float* src = (m < 32) ? (wf + m * 64) : (wg + (m - 32) * 64);
    unsigned short l0, l1;
    unsigned ph = pack2(src[2 * k2], src[2 * k2 + 1], &l0, &l1);
    *(unsigned*)&Wh[m][2 * k2] = ph;
    *(unsigned*)&Wl[m][2 * k2] = (unsigned)l0 | ((unsigned)l1 << 16);
  }
  // ---- stage X tile ----
  for (int i = tid; i < 32 * TB; i += 256) {
    int col = i & (TB - 1), c = i >> 6;
    int e0 = jb + col - pad;
    int e1 = e0 + d;
    float v0 = (e0 >= 0 && e0 < Told) ? xin[(size_t)c * LBUF + e0] : 0.0f;
    float v1 = (e1 >= 0 && e1 < Told) ? xin[(size_t)c * LBUF + e1] : 0.0f;
    unsigned short l0, l1;
    unsigned ph = pack2(v0, v1, &l0, &l1);
    *(unsigned*)&Xh[col][2 * c] = ph;
    *(unsigned*)&Xl[col][2 * c] = (unsigned)l0 | ((unsigned)l1 << 16);
  }
  __syncthreads();

  // ---- GEMM1: K=64, 3-term split ----
  f32x4 acc1[4];
#pragma unroll
  for (int mt = 0; mt < 4; ++mt) acc1[mt] = (f32x4){0.f, 0.f, 0.f, 0.f};
#pragma unroll
  for (int ks = 0; ks < 2; ++ks) {
    const char* xb = (const char*)&Xh[0][0] + (w * 16 + lr) * 144 + ks * 64 + lg * 16;
    const char* xl = (const char*)&Xl[0][0] + (w * 16 + lr) * 144 + ks * 64 + lg * 16;
    bf16x8 bh = *(const bf16x8*)xb;
    bf16x8 bl = *(const bf16x8*)xl;
#pragma unroll
    for (int mt = 0; mt < 4; ++mt) {
      const char* wb  = (const char*)&Wh[0][0] + (mt * 16 + lr) * 144 + ks * 64 + lg * 16;
      const char* wlp = (const char*)&Wl[0][0] + (mt * 16 + lr) * 144 + ks * 64 + lg * 16;
      bf16x8 ah = *(const bf16x8*)wb;
      bf16x8 al = *(const bf16x8*)wlp;
      acc1[mt] = __builtin_amdgcn_mfma_f32_16x16x32_bf16(ah, bh, acc1[mt], 0, 0, 0);
      acc1[mt] = __builtin_amdgcn_mfma_f32_16x16x32_bf16(ah, bl, acc1[mt], 0, 0, 0);
      acc1[mt] = __builtin_amdgcn_mfma_f32_16x16x32_bf16(al, bh, acc1[mt], 0, 0, 0);
    }
  }

  // ---- gate -> Gh/Gl (wave-local cols) ----
  {
    int col = w * 16 + lr;
#pragma unroll
    for (int t = 0; t < 2; ++t) {
      float g0 = ftanh(acc1[t][0]) * ftanh(acc1[t + 2][0]);
      float g1 = ftanh(acc1[t][1]) * ftanh(acc1[t + 2][1]);
      float g2 = ftanh(acc1[t][2]) * ftanh(acc1[t + 2][2]);
      float g3 = ftanh(acc1[t][3]) * ftanh(acc1[t + 2][3]);
      int o0 = t * 16 + lg * 4;
      unsigned short l0, l1, l2, l3;
      unsigned p01 = pack2(g0, g1, &l0, &l1);
      unsigned p23 = pack2(g2, g3, &l2, &l3);
      *(unsigned*)&Gh[col][o0]     = p01;
      *(unsigned*)&Gh[col][o0 + 2] = p23;
      *(unsigned*)&Gl[col][o0]     = (unsigned)l0 | ((unsigned)l1 << 16);
      *(unsigned*)&Gl[col][o0 + 2] = (unsigned)l2 | ((unsigned)l3 << 16);
    }
  }

  // ---- GEMM2: K=32, 3-term, A from regs; wave-local B ----
  f32x4 acc2[3];
  {
    const char* gb = (const char*)&Gh[0][0] + (w * 16 + lr) * 80 + lg * 16;
    const char* gl = (const char*)&Gl[0][0] + (w * 16 + lr) * 80 + lg * 16;
    bf16x8 bh = *(const bf16x8*)gb;
    bf16x8 bl = *(const bf16x8*)gl;
#pragma unroll
    for (int mt = 0; mt < 3; ++mt) {
      f32x4 z = {0.f, 0.f, 0.f, 0.f};
      z = __builtin_amdgcn_mfma_f32_16x16x32_bf16(a2h[mt], bh, z, 0, 0, 0);
      z = __builtin_amdgcn_mfma_f32_16x16x32_bf16(a2h[mt], bl, z, 0, 0, 0);
      acc2[mt] = __builtin_amdgcn_mfma_f32_16x16x32_bf16(a2l[mt], bh, z, 0, 0, 0);
    }
  }

  __syncthreads();   // all GEMM1 reads of Wh/Wl done -> reuse as OutS
  {
    int col = w * 16 + lr;
#pragma unroll
    for (int mt = 0; mt < 2; ++mt)
#pragma unroll
      for (int i = 0; i < 4; ++i) {
        int m = mt * 16 + lg * 4 + i;
        float xr = bf2f(Xh[col][2 * m + 1]) + bf2f(Xl[col][2 * m + 1]);
        OutS[m][col] = acc2[mt][i] + xr;
      }
#pragma unroll
    for (int i = 0; i < 4; ++i)
      OutS[32 + lg * 4 + i][col] = acc2[2][i];
  }
  __syncthreads();

  bool fullN = (jb + TB <= Tn);
  if (writex) {
    if (fullN) {
      int r = tid >> 3, cb = (tid & 7) * 8;
      size_t base = (size_t)r * LBUF + jb + cb;
      float4 v0 = *(float4*)&OutS[r][cb];
      float4 v1 = *(float4*)&OutS[r][cb + 4];
      *(float4*)&xout[base]     = v0;
      *(float4*)&xout[base + 4] = v1;
    } else {
      int c = tid & 63, r0 = tid >> 6;
      int j = jb + c;
      if (j < Tn)
#pragma unroll
        for (int rr = r0; rr < 32; rr += 4)
          xout[(size_t)rr * LBUF + j] = OutS[rr][c];
    }
  }
  if (fullN && ((off_s & 3) == 0) && jb >= off_s) {
    int r = tid >> 4, cb = (tid & 15) * 4;
    size_t base = (size_t)r * TF + (jb - off_s) + cb;
    float4 v = *(float4*)&OutS[32 + r][cb];
    if (first) {
      *(float4*)&skip[base] = v;
    } else {
      float4 o = *(const float4*)&skip[base];
      o.x += v.x; o.y += v.y; o.z += v.z; o.w += v.w;
      *(float4*)&skip[base] = o;
    }
  } else {
    int c = tid & 63, r0 = tid >> 6;
    int j = jb + c, js = j - off_s;
    if (j < Tn && js >= 0) {
#pragma unroll
      for (int rr = r0; rr < 16; rr += 4) {
        if (first) skip[(size_t)rr * TF + js]  = OutS[32 + rr][c];
        else       skip[(size_t)rr * TF + js] += OutS[32 + rr][c];
      }
    }
  }
}

// Fused final MLP: out = W2 @ relu(W1 @ relu(skip)). H1 bf16 in LDS; W2 split chunks.
__global__ __launch_bounds__(256) void k_final(
    const float* __restrict__ skip,
    const float* __restrict__ w1, const float* __restrict__ w2,
    float* __restrict__ out)
{
  __shared__ alignas(16) char smem[74752];
  unsigned short (*H1)[264]  = (unsigned short (*)[264])&smem[0];      // 33792
  unsigned short (*SKh)[40]  = (unsigned short (*)[40])&smem[33792];   // 5120
  unsigned short (*SKl)[40]  = (unsigned short (*)[40])&smem[38912];   // 5120
  unsigned short (*W2ch)[40] = (unsigned short (*)[40])&smem[33792];   // 20480
  unsigned short (*W2cl)[40] = (unsigned short (*)[40])&smem[54272];   // 20480
  float (*OutS)[68] = (float (*)[68])&smem[0];                          // 69632

  int tid = threadIdx.x;
  int jb  = blockIdx.x * 64;
  int lane = tid & 63, w = tid >> 6;
  int lr = lane & 15, lg = lane >> 4;
  int col = w * 16 + lr;

  for (int i = tid; i < 1024; i += 256) {
    int c = i & 63, k2 = i >> 6;
    float v0 = (2 * k2 < 16)     ? fmaxf(skip[(size_t)(2 * k2) * TF + jb + c], 0.f) : 0.f;
    float v1 = (2 * k2 + 1 < 16) ? fmaxf(skip[(size_t)(2 * k2 + 1) * TF + jb + c], 0.f) : 0.f;
    unsigned short l0, l1;
    unsigned ph = pack2(v0, v1, &l0, &l1);
    *(unsigned*)&SKh[c][2 * k2] = ph;
    *(unsigned*)&SKl[c][2 * k2] = (unsigned)l0 | ((unsigned)l1 << 16);
  }
  __syncthreads();

  // GEMM1: 3-term split; h1 -> H1 bf16 (wave-local cols)
  {
    bf16x8 bh = *(const bf16x8*)((const char*)&SKh[0][0] + col * 80 + lg * 16);
    bf16x8 bl = *(const bf16x8*)((const char*)&SKl[0][0] + col * 80 + lg * 16);
#pragma unroll 4
    for (int mt = 0; mt < 16; ++mt) {
      bf16x8 ah = {0, 0, 0, 0, 0, 0, 0, 0};
      bf16x8 al = {0, 0, 0, 0, 0, 0, 0, 0};
      if (lg < 2) {
        int m = mt * 16 + lr;
#pragma unroll
        for (int jj = 0; jj < 8; ++jj) {
          float f = w1[m * 16 + lg * 8 + jj];
          unsigned short h = b16(f);
          ah[jj] = (short)h;
          al[jj] = (short)b16(f - bf2f(h));
        }
      }
      f32x4 z = {0.f, 0.f, 0.f, 0.f};
      z = __builtin_amdgcn_mfma_f32_16x16x32_bf16(ah, bh, z, 0, 0, 0);
      z = __builtin_amdgcn_mfma_f32_16x16x32_bf16(ah, bl, z, 0, 0, 0);
      z = __builtin_amdgcn_mfma_f32_16x16x32_bf16(al, bh, z, 0, 0, 0);
      int q0 = mt * 16 + lg * 4;
      unsigned p01 = (unsigned)b16(fmaxf(z[0], 0.f)) | ((unsigned)b16(fmaxf(z[1], 0.f)) << 16);
      unsigned p23 = (unsigned)b16(fmaxf(z[2], 0.f)) | ((unsigned)b16(fmaxf(z[3], 0.f)) << 16);
      *(unsigned*)&H1[col][q0]     = p01;
      *(unsigned*)&H1[col][q0 + 2] = p23;
    }
  }

  f32x4 acco[16];
#pragma unroll
  for (int mt = 0; mt < 16; ++mt) acco[mt] = (f32x4){0.f, 0.f, 0.f, 0.f};

  for (int kb = 0; kb < 8; ++kb) {
    __syncthreads();  // iter0: GEMM1 done before SK overwritten; else: prev reads done
    for (int i = tid; i < 4096; i += 256) {
      int q = i >> 4, k2 = i & 15;
      unsigned short l0, l1;
      unsigned ph = pack2(w2[q * 256 + kb * 32 + 2 * k2],
                          w2[q * 256 + kb * 32 + 2 * k2 + 1], &l0, &l1);
      *(unsigned*)&W2ch[q][2 * k2] = ph;
      *(unsigned*)&W2cl[q][2 * k2] = (unsigned)l0 | ((unsigned)l1 << 16);
    }
    __syncthreads();
    bf16x8 bh = *(const bf16x8*)((const char*)&H1[0][0] + col * 528 + kb * 64 + lg * 16);
    // FULL unroll: acco must be statically indexed (rule #20 — unroll-4 spilled it to scratch)
#pragma unroll
    for (int mt = 0; mt < 16; ++mt) {
      bf16x8 ah = *(const bf16x8*)((const char*)&W2ch[0][0] + (mt * 16 + lr) * 80 + lg * 16);
      bf16x8 al = *(const bf16x8*)((const char*)&W2cl[0][0] + (mt * 16 + lr) * 80 + lg * 16);
      acco[mt] = __builtin_amdgcn_mfma_f32_16x16x32_bf16(ah, bh, acco[mt], 0, 0, 0);
      acco[mt] = __builtin_amdgcn_mfma_f32_16x16x32_bf16(al, bh, acco[mt], 0, 0, 0);
    }
  }

  __syncthreads();
#pragma unroll
  for (int mt = 0; mt < 16; ++mt)
#pragma unroll
    for (int i = 0; i < 4; ++i)
      OutS[mt * 16 + lg * 4 + i][col] = acco[mt][i];
  __syncthreads();

  int ty = tid >> 3, tx = tid & 7;
#pragma unroll
  for (int i = 0; i < 8; ++i) {
    int q = ty * 8 + i;
    float4 v0 = *(float4*)&OutS[q][tx * 8];
    float4 v1 = *(float4*)&OutS[q][tx * 8 + 4];
    size_t base = (size_t)q * TF + jb + tx * 8;
    *(float4*)&out[base]     = v0;
    *(float4*)&out[base + 4] = v1;
  }
}

extern "C" void kernel_launch(void* const* d_in, const int* in_sizes, int n_in,
                              void* d_out, int out_size, void* d_ws, size_t ws_size,
                              hipStream_t stream) {
  const float* x_in     = (const float*)d_in[0];
  const float* w_init   = (const float*)d_in[1];
  const float* w_filter = (const float*)d_in[2];
  const float* w_gate   = (const float*)d_in[3];
  const float* w_res    = (const float*)d_in[4];
  const float* w_skip   = (const float*)d_in[5];
  const float* w_f1     = (const float*)d_in[6];
  const float* w_f2     = (const float*)d_in[7];
  float* out = (float*)d_out;

  float* xa    = (float*)d_ws;
  float* xb    = xa + 32 * (size_t)LBUF;
  float* skipb = xb + 32 * (size_t)LBUF;

  k_init<<<LBUF / 1024, 256, 0, stream>>>(x_in, w_init, xa);

  int T = LBUF;
  for (int idx = 0; idx < 20; ++idx) {
    int d    = 1 << (idx % 10);
    int pad  = (d - (T % d)) % d;
    int Tn   = T + pad - d;
    int offs = Tn - TF;
    k_layer<<<(Tn + TB - 1) / TB, 256, 0, stream>>>(
        xa, xb, skipb,
        w_filter + (size_t)idx * 2048, w_gate + (size_t)idx * 2048,
        w_res + (size_t)idx * 1024, w_skip + (size_t)idx * 512,
        Tn, T, d, pad, offs, (idx == 0) ? 1 : 0, (idx == 19) ? 0 : 1);
    float* t = xa; xa = xb; xb = t;
    T = Tn;
  }

  k_final<<<TF / 64, 256, 0, stream>>>(skipb, w_f1, w_f2, out);
}

// Round 10
// 775.246 us; speedup vs baseline: 2.6228x; 1.1327x over previous
//
#include <hip/hip_runtime.h>

#define LBUF 131072
#define TF   130048
#define TB   64

typedef short bf16x8 __attribute__((ext_vector_type(8)));
typedef float f32x4  __attribute__((ext_vector_type(4)));

__device__ __forceinline__ float ftanh(float x) {
  float ax = fminf(fabsf(x), 15.0f);
  float t  = __expf(2.0f * ax);
  float r  = 1.0f - 2.0f / (t + 1.0f);
  return copysignf(r, x);
}
__device__ __forceinline__ unsigned short b16(float f) {
  unsigned u = __builtin_bit_cast(unsigned, f);
  return (unsigned short)((u + 0x7fffu + ((u >> 16) & 1u)) >> 16);
}
__device__ __forceinline__ float bf2f(unsigned short h) {
  return __builtin_bit_cast(float, ((unsigned)h) << 16);
}

__global__ void k_init(const float* __restrict__ in, const float* __restrict__ w_init,
                       float* __restrict__ x) {
  int t = blockIdx.x * blockDim.x + threadIdx.x;
  int j = t * 4;
  if (j >= LBUF) return;
  float4 v = *(const float4*)&in[j];
#pragma unroll
  for (int c = 0; c < 32; ++c) {
    float s = w_init[c];
    float4 o = {s * v.x, s * v.y, s * v.z, s * v.w};
    *(float4*)&x[(size_t)c * LBUF + j] = o;
  }
}

// Pre-pack all weights into split hi/lo bf16 planes (runs once per call, ~182k elems).
// whp:  [20][64 m][128] (k hi 0..63 | k lo 64..127)
// w2p:  [20][48 m][64]  (o hi 0..31 | o lo 32..63)
// w1p:  [256 q][32]     (k hi 0..15 | k lo 16..31)
// w2fp: [256 q][512]    (k hi 0..255 | k lo 256..511)
__global__ __launch_bounds__(256) void k_pack(
    const float* __restrict__ wf, const float* __restrict__ wg,
    const float* __restrict__ wr, const float* __restrict__ wsk,
    const float* __restrict__ w1, const float* __restrict__ w2,
    unsigned short* __restrict__ whp, unsigned short* __restrict__ w2p,
    unsigned short* __restrict__ w1p, unsigned short* __restrict__ w2fp)
{
  int i = blockIdx.x * 256 + threadIdx.x;
  if (i < 81920) {                       // conv weights: 20 x 4096
    int l = i >> 12, r = i & 4095;
    int m = r >> 6, k = r & 63;
    float v = (m < 32) ? wf[l * 2048 + m * 64 + k] : wg[l * 2048 + (m - 32) * 64 + k];
    unsigned short h = b16(v);
    whp[l * 8192 + m * 128 + k]      = h;
    whp[l * 8192 + m * 128 + 64 + k] = b16(v - bf2f(h));
  } else if (i < 112640) {               // 1x1 weights: 20 x 1536
    int t = i - 81920;
    int l = t / 1536, r = t - l * 1536;
    int m = r >> 5, o = r & 31;
    float v = (m < 32) ? wr[l * 1024 + m * 32 + o] : wsk[l * 512 + (m - 32) * 32 + o];
    unsigned short h = b16(v);
    w2p[l * 3072 + m * 64 + o]      = h;
    w2p[l * 3072 + m * 64 + 32 + o] = b16(v - bf2f(h));
  } else if (i < 116736) {               // W1: 4096
    int t = i - 112640;
    int q = t >> 4, k = t & 15;
    float v = w1[q * 16 + k];
    unsigned short h = b16(v);
    w1p[q * 32 + k]      = h;
    w1p[q * 32 + 16 + k] = b16(v - bf2f(h));
  } else {                               // W2: 65536
    int t = i - 116736;
    int q = t >> 8, k = t & 255;
    float v = w2[q * 256 + k];
    unsigned short h = b16(v);
    w2fp[q * 512 + k]       = h;
    w2fp[q * 512 + 256 + k] = b16(v - bf2f(h));
  }
}

// One dilated layer: split-bf16 MFMA, XOR-swizzled LDS (conflict-free fragment reads).
__global__ __launch_bounds__(256) void k_layer(
    const float* __restrict__ xin, float* __restrict__ xout,
    float* __restrict__ skip,
    const unsigned* __restrict__ wsrc,        // this layer's packed conv w, 4096 u32
    const unsigned short* __restrict__ w2p,   // this layer's packed 1x1, [48][64]
    int Tn, int Told, int d, int pad, int off_s, int first, int writex)
{
  __shared__ alignas(16) char xs[16384];   // X [64 col][256B: hi|lo], swz ^((col&15)<<4)
  __shared__ alignas(16) char gs[8192];    // G [64 col][128B: hi|lo], swz ^((col&7)<<4)
  __shared__ alignas(16) char wbuf[16384]; // W [64 m][256B: hi|lo], swz ^((m&15)<<4); later OutS
  float (*OutS)[68] = (float (*)[68])&wbuf[0];   // 48 x 68 x 4 = 13056 B

  int tid = threadIdx.x;
  int jb  = blockIdx.x * TB;
  int lane = tid & 63, w = tid >> 6;
  int lr = lane & 15, lg = lane >> 4;

  // 1x1 fragments straight from packed global (L1/L2-hot, no conversion)
  bf16x8 a2h[3], a2l[3];
#pragma unroll
  for (int mt = 0; mt < 3; ++mt) {
    int m = mt * 16 + lr;
    a2h[mt] = *(const bf16x8*)(w2p + m * 64 + lg * 8);
    a2l[mt] = *(const bf16x8*)(w2p + m * 64 + 32 + lg * 8);
  }

  // conv weights: pure u32 copies into swizzled LDS
  for (int i = tid; i < 4096; i += 256) {
    int m = i >> 6, j = i & 63;
    *(unsigned*)(wbuf + ((m * 256 + j * 4) ^ ((m & 15) << 4))) = wsrc[i];
  }
  // X tile: fp32 -> split bf16 (data-dependent, must pack here)
  for (int i = tid; i < 2048; i += 256) {
    int col = i & 63, c = i >> 6;
    int e0 = jb + col - pad, e1 = e0 + d;
    float v0 = (e0 >= 0 && e0 < Told) ? xin[(size_t)c * LBUF + e0] : 0.f;
    float v1 = (e1 < Told) ? xin[(size_t)c * LBUF + e1] : 0.f;
    unsigned short h0 = b16(v0), h1 = b16(v1);
    unsigned short l0 = b16(v0 - bf2f(h0)), l1 = b16(v1 - bf2f(h1));
    unsigned sw = (unsigned)(col & 15) << 4;
    *(unsigned*)(xs + ((col * 256 + c * 4) ^ sw))       = (unsigned)h0 | ((unsigned)h1 << 16);
    *(unsigned*)(xs + ((col * 256 + 128 + c * 4) ^ sw)) = (unsigned)l0 | ((unsigned)l1 << 16);
  }
  __syncthreads();

  int col = w * 16 + lr;
  unsigned swx = (unsigned)lr << 4;   // (col&15)==lr; (row&15)==lr for W rows

  // ---- GEMM1: K=64, 3-term split ----
  f32x4 acc1[4];
#pragma unroll
  for (int mt = 0; mt < 4; ++mt) acc1[mt] = (f32x4){0.f, 0.f, 0.f, 0.f};
#pragma unroll
  for (int ks = 0; ks < 2; ++ks) {
    bf16x8 bh = *(const bf16x8*)(xs + ((col * 256 + ks * 64 + lg * 16) ^ swx));
    bf16x8 bl = *(const bf16x8*)(xs + ((col * 256 + 128 + ks * 64 + lg * 16) ^ swx));
#pragma unroll
    for (int mt = 0; mt < 4; ++mt) {
      int row = mt * 16 + lr;
      bf16x8 ah = *(const bf16x8*)(wbuf + ((row * 256 + ks * 64 + lg * 16) ^ swx));
      bf16x8 al = *(const bf16x8*)(wbuf + ((row * 256 + 128 + ks * 64 + lg * 16) ^ swx));
      acc1[mt] = __builtin_amdgcn_mfma_f32_16x16x32_bf16(ah, bh, acc1[mt], 0, 0, 0);
      acc1[mt] = __builtin_amdgcn_mfma_f32_16x16x32_bf16(ah, bl, acc1[mt], 0, 0, 0);
      acc1[mt] = __builtin_amdgcn_mfma_f32_16x16x32_bf16(al, bh, acc1[mt], 0, 0, 0);
    }
  }

  // ---- gate -> gs (wave-local) ----
  unsigned swg = (unsigned)(col & 7) << 4;
#pragma unroll
  for (int t = 0; t < 2; ++t) {
    float g0 = ftanh(acc1[t][0]) * ftanh(acc1[t + 2][0]);
    float g1 = ftanh(acc1[t][1]) * ftanh(acc1[t + 2][1]);
    float g2 = ftanh(acc1[t][2]) * ftanh(acc1[t + 2][2]);
    float g3 = ftanh(acc1[t][3]) * ftanh(acc1[t + 2][3]);
    unsigned short h0 = b16(g0), h1 = b16(g1), h2 = b16(g2), h3 = b16(g3);
    unsigned short l0 = b16(g0 - bf2f(h0)), l1 = b16(g1 - bf2f(h1));
    unsigned short l2 = b16(g2 - bf2f(h2)), l3 = b16(g3 - bf2f(h3));
    int ob = (t * 16 + lg * 4) * 2;
    *(unsigned*)(gs + ((col * 128 + ob) ^ swg))          = (unsigned)h0 | ((unsigned)h1 << 16);
    *(unsigned*)(gs + ((col * 128 + ob + 4) ^ swg))      = (unsigned)h2 | ((unsigned)h3 << 16);
    *(unsigned*)(gs + ((col * 128 + 64 + ob) ^ swg))     = (unsigned)l0 | ((unsigned)l1 << 16);
    *(unsigned*)(gs + ((col * 128 + 64 + ob + 4) ^ swg)) = (unsigned)l2 | ((unsigned)l3 << 16);
  }

  // ---- GEMM2: K=32, 3-term, A regs; wave-local B ----
  f32x4 acc2[3];
  {
    bf16x8 bgh = *(const bf16x8*)(gs + ((col * 128 + lg * 16) ^ swg));
    bf16x8 bgl = *(const bf16x8*)(gs + ((col * 128 + 64 + lg * 16) ^ swg));
#pragma unroll
    for (int mt = 0; mt < 3; ++mt) {
      f32x4 z = {0.f, 0.f, 0.f, 0.f};
      z = __builtin_amdgcn_mfma_f32_16x16x32_bf16(a2h[mt], bgh, z, 0, 0, 0);
      z = __builtin_amdgcn_mfma_f32_16x16x32_bf16(a2h[mt], bgl, z, 0, 0, 0);
      acc2[mt] = __builtin_amdgcn_mfma_f32_16x16x32_bf16(a2l[mt], bgh, z, 0, 0, 0);
    }
  }

  __syncthreads();   // Ws reads done -> reuse wbuf as OutS
  {
#pragma unroll
    for (int mt = 0; mt < 2; ++mt)
#pragma unroll
      for (int i = 0; i < 4; ++i) {
        int m = mt * 16 + lg * 4 + i;
        unsigned short xh = *(unsigned short*)(xs + ((col * 256 + (2 * m + 1) * 2) ^ swx));
        unsigned short xl = *(unsigned short*)(xs + ((col * 256 + 128 + (2 * m + 1) * 2) ^ swx));
        OutS[m][col] = acc2[mt][i] + (bf2f(xh) + bf2f(xl));
      }
#pragma unroll
    for (int i = 0; i < 4; ++i)
      OutS[32 + lg * 4 + i][col] = acc2[2][i];
  }
  __syncthreads();

  bool fullN = (jb + TB <= Tn);
  if (writex) {
    if (fullN) {
      int r = tid >> 3, cb = (tid & 7) * 8;
      size_t base = (size_t)r * LBUF + jb + cb;
      float4 v0 = *(float4*)&OutS[r][cb];
      float4 v1 = *(float4*)&OutS[r][cb + 4];
      *(float4*)&xout[base]     = v0;
      *(float4*)&xout[base + 4] = v1;
    } else {
      int c = tid & 63, r0 = tid >> 6;
      int j = jb + c;
      if (j < Tn)
#pragma unroll
        for (int rr = r0; rr < 32; rr += 4)
          xout[(size_t)rr * LBUF + j] = OutS[rr][c];
    }
  }
  if (fullN && ((off_s & 3) == 0) && jb >= off_s) {
    int r = tid >> 4, cb = (tid & 15) * 4;
    size_t base = (size_t)r * TF + (jb - off_s) + cb;
    float4 v = *(float4*)&OutS[32 + r][cb];
    if (first) {
      *(float4*)&skip[base] = v;
    } else {
      float4 o = *(const float4*)&skip[base];
      o.x += v.x; o.y += v.y; o.z += v.z; o.w += v.w;
      *(float4*)&skip[base] = o;
    }
  } else {
    int c = tid & 63, r0 = tid >> 6;
    int j = jb + c, js = j - off_s;
    if (j < Tn && js >= 0) {
#pragma unroll
      for (int rr = r0; rr < 16; rr += 4) {
        if (first) skip[(size_t)rr * TF + js]  = OutS[32 + rr][c];
        else       skip[(size_t)rr * TF + js] += OutS[32 + rr][c];
      }
    }
  }
}

// Fused final MLP. W1/W2 fragments per-lane from packed global; H1 hi-bf16 in swizzled LDS.
__global__ __launch_bounds__(256) void k_final(
    const float* __restrict__ skip,
    const unsigned short* __restrict__ w1p,   // [256][32]
    const unsigned short* __restrict__ w2fp,  // [256][512]
    float* __restrict__ out)
{
  __shared__ alignas(16) char smem[69632];
  char* sks = smem;             // [64 col][128B: hi|lo], swz ^((col&7)<<4)   (8 KB)
  char* h1s = smem + 8192;      // [64 col][512B hi], swz ^((col&31)<<4)     (32 KB)
  float (*OutS)[68] = (float (*)[68])&smem[0];   // 256 x 68 x 4 = 69632

  int tid = threadIdx.x;
  int jb  = blockIdx.x * 64;
  int lane = tid & 63, w = tid >> 6;
  int lr = lane & 15, lg = lane >> 4;
  int col = w * 16 + lr;

  for (int i = tid; i < 1024; i += 256) {
    int c = i & 63, k2 = i >> 6;
    float v0 = (2 * k2 < 16)     ? fmaxf(skip[(size_t)(2 * k2) * TF + jb + c], 0.f) : 0.f;
    float v1 = (2 * k2 + 1 < 16) ? fmaxf(skip[(size_t)(2 * k2 + 1) * TF + jb + c], 0.f) : 0.f;
    unsigned short h0 = b16(v0), h1 = b16(v1);
    unsigned short l0 = b16(v0 - bf2f(h0)), l1 = b16(v1 - bf2f(h1));
    unsigned sw = (unsigned)(c & 7) << 4;
    *(unsigned*)(sks + ((c * 128 + k2 * 4) ^ sw))      = (unsigned)h0 | ((unsigned)h1 << 16);
    *(unsigned*)(sks + ((c * 128 + 64 + k2 * 4) ^ sw)) = (unsigned)l0 | ((unsigned)l1 << 16);
  }
  __syncthreads();

  unsigned swk = (unsigned)(col & 7) << 4;
  unsigned swh = (unsigned)(col & 31) << 4;

  // GEMM1 -> H1 (wave-local handoff, no barrier)
  {
    bf16x8 bh = *(const bf16x8*)(sks + ((col * 128 + lg * 16) ^ swk));
    bf16x8 bl = *(const bf16x8*)(sks + ((col * 128 + 64 + lg * 16) ^ swk));
#pragma unroll
    for (int mt = 0; mt < 16; ++mt) {
      bf16x8 ah = {0, 0, 0, 0, 0, 0, 0, 0};
      bf16x8 al = {0, 0, 0, 0, 0, 0, 0, 0};
      if (lg < 2) {
        int m = mt * 16 + lr;
        ah = *(const bf16x8*)(w1p + m * 32 + lg * 8);
        al = *(const bf16x8*)(w1p + m * 32 + 16 + lg * 8);
      }
      f32x4 z = {0.f, 0.f, 0.f, 0.f};
      z = __builtin_amdgcn_mfma_f32_16x16x32_bf16(ah, bh, z, 0, 0, 0);
      z = __builtin_amdgcn_mfma_f32_16x16x32_bf16(ah, bl, z, 0, 0, 0);
      z = __builtin_amdgcn_mfma_f32_16x16x32_bf16(al, bh, z, 0, 0, 0);
      int qb = (mt * 16 + lg * 4) * 2;
      unsigned p01 = (unsigned)b16(fmaxf(z[0], 0.f)) | ((unsigned)b16(fmaxf(z[1], 0.f)) << 16);
      unsigned p23 = (unsigned)b16(fmaxf(z[2], 0.f)) | ((unsigned)b16(fmaxf(z[3], 0.f)) << 16);
      *(unsigned*)(h1s + ((col * 512 + qb) ^ swh))     = p01;
      *(unsigned*)(h1s + ((col * 512 + qb + 4) ^ swh)) = p23;
    }
  }

  // GEMM2: K=256 in 8 chunks; W2 fragments per-lane from global, no barriers
  f32x4 acco[16];
#pragma unroll
  for (int mt = 0; mt < 16; ++mt) acco[mt] = (f32x4){0.f, 0.f, 0.f, 0.f};

  for (int kb = 0; kb < 8; ++kb) {
    bf16x8 bh = *(const bf16x8*)(h1s + ((col * 512 + kb * 64 + lg * 16) ^ swh));
#pragma unroll
    for (int mt = 0; mt < 16; ++mt) {
      const unsigned short* wq = w2fp + (mt * 16 + lr) * 512 + kb * 32 + lg * 8;
      bf16x8 ah = *(const bf16x8*)(wq);
      bf16x8 al = *(const bf16x8*)(wq + 256);
      acco[mt] = __builtin_amdgcn_mfma_f32_16x16x32_bf16(ah, bh, acco[mt], 0, 0, 0);
      acco[mt] = __builtin_amdgcn_mfma_f32_16x16x32_bf16(al, bh, acco[mt], 0, 0, 0);
    }
  }

  __syncthreads();   // all H1 reads done -> reuse smem as OutS
#pragma unroll
  for (int mt = 0; mt < 16; ++mt)
#pragma unroll
    for (int i = 0; i < 4; ++i)
      OutS[mt * 16 + lg * 4 + i][col] = acco[mt][i];
  __syncthreads();

  int ty = tid >> 3, tx = tid & 7;
#pragma unroll
  for (int i = 0; i < 8; ++i) {
    int q = ty * 8 + i;
    float4 v0 = *(float4*)&OutS[q][tx * 8];
    float4 v1 = *(float4*)&OutS[q][tx * 8 + 4];
    size_t base = (size_t)q * TF + jb + tx * 8;
    *(float4*)&out[base]     = v0;
    *(float4*)&out[base + 4] = v1;
  }
}

extern "C" void kernel_launch(void* const* d_in, const int* in_sizes, int n_in,
                              void* d_out, int out_size, void* d_ws, size_t ws_size,
                              hipStream_t stream) {
  const float* x_in     = (const float*)d_in[0];
  const float* w_init   = (const float*)d_in[1];
  const float* w_filter = (const float*)d_in[2];
  const float* w_gate   = (const float*)d_in[3];
  const float* w_res    = (const float*)d_in[4];
  const float* w_skip   = (const float*)d_in[5];
  const float* w_f1     = (const float*)d_in[6];
  const float* w_f2     = (const float*)d_in[7];
  float* out = (float*)d_out;

  float* xa    = (float*)d_ws;
  float* xb    = xa + 32 * (size_t)LBUF;
  float* skipb = xb + 32 * (size_t)LBUF;
  unsigned short* whp  = (unsigned short*)(skipb + 16 * (size_t)TF);
  unsigned short* w2p  = whp + 20 * 8192;
  unsigned short* w1p  = w2p + 20 * 3072;
  unsigned short* w2fp = w1p + 8192;

  k_init<<<LBUF / 1024, 256, 0, stream>>>(x_in, w_init, xa);
  k_pack<<<712, 256, 0, stream>>>(w_filter, w_gate, w_res, w_skip, w_f1, w_f2,
                                  whp, w2p, w1p, w2fp);

  int T = LBUF;
  for (int idx = 0; idx < 20; ++idx) {
    int d    = 1 << (idx % 10);
    int pad  = (d - (T % d)) % d;
    int Tn   = T + pad - d;
    int offs = Tn - TF;
    k_layer<<<(Tn + TB - 1) / TB, 256, 0, stream>>>(
        xa, xb, skipb,
        (const unsigned*)(whp + (size_t)idx * 8192), w2p + (size_t)idx * 3072,
        Tn, T, d, pad, offs, (idx == 0) ? 1 : 0, (idx == 19) ? 0 : 1);
    float* t = xa; xa = xb; xb = t;
    T = Tn;
  }

  k_final<<<TF / 64, 256, 0, stream>>>(skipb, w1p, w2fp, out);
}